// Round 4
// baseline (3850.418 us; speedup 1.0000x reference)
//
#include <hip/hip_runtime.h>
#include <hip/hip_bf16.h>
#include <math.h>

#define DIM 512
#define SEQ 2048
#define NB 2
#define NEG_INF (-1e30f)

typedef __bf16 bf16x8 __attribute__((ext_vector_type(8)));
typedef float f32x4 __attribute__((ext_vector_type(4)));

static __device__ __forceinline__ float wave_sum(float x) {
#pragma unroll
  for (int off = 32; off; off >>= 1) x += __shfl_xor(x, off, 64);
  return x;
}

static __device__ __forceinline__ bf16x8 pack8(float4 a, float4 b) {
  bf16x8 r;
  r[0] = (__bf16)a.x; r[1] = (__bf16)a.y; r[2] = (__bf16)a.z; r[3] = (__bf16)a.w;
  r[4] = (__bf16)b.x; r[5] = (__bf16)b.y; r[6] = (__bf16)b.z; r[7] = (__bf16)b.w;
  return r;
}

static __device__ __forceinline__ void gload16(const void* g, void* l) {
  __builtin_amdgcn_global_load_lds((const __attribute__((address_space(1))) void*)g,
                                   (__attribute__((address_space(3))) void*)l, 16, 0, 0);
}

// sorted top-4 insert, strict >, earlier-inserted wins ties (callers insert in
// ascending-index order so ties keep the lower index == jax.lax.top_k)
static __device__ __forceinline__ void ins4(float x, int s, float& v0, float& v1, float& v2,
                                            float& v3, int& i0, int& i1, int& i2, int& i3) {
  if (x > v3) {
    if (x > v0) { v3 = v2; i3 = i2; v2 = v1; i2 = i1; v1 = v0; i1 = i0; v0 = x; i0 = s; }
    else if (x > v1) { v3 = v2; i3 = i2; v2 = v1; i2 = i1; v1 = x; i1 = s; }
    else if (x > v2) { v3 = v2; i3 = i2; v2 = x; i2 = s; }
    else { v3 = x; i3 = s; }
  }
}

// ---------------- embed gather ----------------
__global__ __launch_bounds__(128) void k_embed(const int* __restrict__ tok,
                                               const float* __restrict__ emb,
                                               float* __restrict__ sS,
                                               float* __restrict__ sV) {
  long row = blockIdx.x;
  int t = tok[row];
  const float4* src = (const float4*)(emb + (long)t * DIM);
  float4* a = (float4*)(sS + row * DIM);
  float4* b = (float4*)(sV + row * DIM);
  int i = threadIdx.x;
  float4 v = src[i];
  a[i] = v;
  b[i] = v;
}

// ---------------- broadcast pe -> f32 state/val + zero-padded bf16 mirror ----------------
__global__ __launch_bounds__(256) void k_bcast2(const float* __restrict__ pe,
                                                float* __restrict__ s, float* __restrict__ v,
                                                __bf16* __restrict__ mb, int N, int Npad) {
  int wid = threadIdx.x >> 6, lane = threadIdx.x & 63;
  long row = (long)blockIdx.x * 4 + wid;
  if (row >= (long)NB * Npad) return;
  int b = (int)(row / Npad), m = (int)(row % Npad);
  int d0 = lane * 8;
  if (m < N) {
    float4 x0 = *(const float4*)(pe + (long)m * DIM + d0);
    float4 x1 = *(const float4*)(pe + (long)m * DIM + d0 + 4);
    long fo = ((long)b * N + m) * DIM + d0;
    *(float4*)(s + fo) = x0; *(float4*)(s + fo + 4) = x1;
    *(float4*)(v + fo) = x0; *(float4*)(v + fo + 4) = x1;
    *(bf16x8*)(mb + row * DIM + d0) = pack8(x0, x1);
  } else {
    bf16x8 z;
#pragma unroll
    for (int i = 0; i < 8; ++i) z[i] = (__bf16)0.f;
    *(bf16x8*)(mb + row * DIM + d0) = z;
  }
}

// ------- A-side cvt: bf16 out[b*CStride + rowOff + m][:] = state*w (pad rows = 0) -------
__global__ __launch_bounds__(256) void k_cvt_aw(const float* __restrict__ in,
                                                const float* __restrict__ w,
                                                __bf16* __restrict__ out, int M, int Mpad,
                                                int rowOff, int CStride) {
  int wid = threadIdx.x >> 6, lane = threadIdx.x & 63;
  long row = (long)blockIdx.x * 4 + wid;
  if (row >= (long)NB * Mpad) return;
  int b = (int)(row / Mpad), m = (int)(row % Mpad);
  int d0 = lane * 8;
  long oo = ((long)b * CStride + rowOff + m) * DIM + d0;
  if (m < M) {
    long fo = ((long)b * M + m) * DIM + d0;
    float4 x0 = *(const float4*)(in + fo);
    float4 x1 = *(const float4*)(in + fo + 4);
    float4 w0 = *(const float4*)(w + d0);
    float4 w1 = *(const float4*)(w + d0 + 4);
    x0.x *= w0.x; x0.y *= w0.y; x0.z *= w0.z; x0.w *= w0.w;
    x1.x *= w1.x; x1.y *= w1.y; x1.z *= w1.z; x1.w *= w1.w;
    *(bf16x8*)(out + oo) = pack8(x0, x1);
  } else {
    bf16x8 z;
#pragma unroll
    for (int i = 0; i < 8; ++i) z[i] = (__bf16)0.f;
    *(bf16x8*)(out + oo) = z;
  }
}

// ---------------- plain f32->bf16 rows (readout A) ----------------
__global__ __launch_bounds__(256) void k_cvt_val(const float* __restrict__ in,
                                                 __bf16* __restrict__ out) {
  int wid = threadIdx.x >> 6, lane = threadIdx.x & 63;
  long row = (long)blockIdx.x * 4 + wid;
  int d0 = lane * 8;
  float4 x0 = *(const float4*)(in + row * DIM + d0);
  float4 x1 = *(const float4*)(in + row * DIM + d0 + 4);
  *(bf16x8*)(out + row * DIM + d0) = pack8(x0, x1);
}

// ---------------- readout_w transpose+cvt: f32[512][32000] -> bf16[32000][512] ----------------
__global__ __launch_bounds__(256) void k_transpose_rw(const float* __restrict__ in,
                                                      __bf16* __restrict__ out) {
  __shared__ float t[32][33];
  int tx = threadIdx.x, ty = threadIdx.y;
  int n0 = blockIdx.x * 32, k0 = blockIdx.y * 32;
#pragma unroll
  for (int i = 0; i < 4; ++i)
    t[ty + i * 8][tx] = in[(long)(k0 + ty + i * 8) * 32000 + n0 + tx];
  __syncthreads();
#pragma unroll
  for (int i = 0; i < 4; ++i)
    out[(long)(n0 + ty + i * 8) * DIM + k0 + tx] = (__bf16)t[tx][ty + i * 8];
}

// ---------------- causal window-4 propagation ----------------
__global__ __launch_bounds__(256) void k_window(const float* __restrict__ sS,
                                                const float* __restrict__ sV,
                                                const float* __restrict__ w,
                                                float* __restrict__ oS,
                                                float* __restrict__ oV,
                                                __bf16* __restrict__ oSb) {
  int wid = threadIdx.x >> 6, lane = threadIdx.x & 63;
  long row = (long)blockIdx.x * 4 + wid;
  int i = (int)(row & (SEQ - 1));
  int d0 = lane * 8;
  const float* ps = sS + row * DIM + d0;
  const float* pv = sV + row * DIM + d0;
  float4 s0 = *(const float4*)ps;
  float4 s1 = *(const float4*)(ps + 4);
  float4 w0 = *(const float4*)(w + d0);
  float4 w1 = *(const float4*)(w + d0 + 4);
  float4 aw0 = make_float4(s0.x * w0.x, s0.y * w0.y, s0.z * w0.z, s0.w * w0.w);
  float4 aw1 = make_float4(s1.x * w1.x, s1.y * w1.y, s1.z * w1.z, s1.w * w1.w);
  float4 nS0[4], nS1[4], nV0[4], nV1[4];
  float sc[4];
#pragma unroll
  for (int k = 0; k < 4; ++k) {
    bool valid = (i >= k + 1);
    const float* qs = ps - (long)(k + 1) * DIM;
    const float* qv = pv - (long)(k + 1) * DIM;
    if (valid) {
      nS0[k] = *(const float4*)qs;
      nS1[k] = *(const float4*)(qs + 4);
      nV0[k] = *(const float4*)qv;
      nV1[k] = *(const float4*)(qv + 4);
    } else {
      nS0[k] = make_float4(0.f, 0.f, 0.f, 0.f);
      nS1[k] = nS0[k]; nV0[k] = nS0[k]; nV1[k] = nS0[k];
    }
    sc[k] = aw0.x * nS0[k].x + aw0.y * nS0[k].y + aw0.z * nS0[k].z + aw0.w * nS0[k].w +
            aw1.x * nS1[k].x + aw1.y * nS1[k].y + aw1.z * nS1[k].z + aw1.w * nS1[k].w;
  }
#pragma unroll
  for (int k = 0; k < 4; ++k) sc[k] = wave_sum(sc[k]);
  float m = NEG_INF;
#pragma unroll
  for (int k = 0; k < 4; ++k)
    if (i >= k + 1 && sc[k] > m) m = sc[k];
  float p[4];
  float Z = 0.f;
#pragma unroll
  for (int k = 0; k < 4; ++k) {
    p[k] = (i >= k + 1) ? expf(sc[k] - m) : 0.f;
    Z += p[k];
  }
  float invZ = (Z > 0.f) ? (1.f / Z) : 0.f;
  float4 v0 = *(const float4*)pv;
  float4 v1 = *(const float4*)(pv + 4);
  float4 os0 = s0, os1 = s1, ov0 = v0, ov1 = v1;
#pragma unroll
  for (int k = 0; k < 4; ++k) {
    float c = 0.25f * p[k] * invZ;
    os0.x += c * nS0[k].x; os0.y += c * nS0[k].y; os0.z += c * nS0[k].z; os0.w += c * nS0[k].w;
    os1.x += c * nS1[k].x; os1.y += c * nS1[k].y; os1.z += c * nS1[k].z; os1.w += c * nS1[k].w;
    ov0.x += c * nV0[k].x; ov0.y += c * nV0[k].y; ov0.z += c * nV0[k].z; ov0.w += c * nV0[k].w;
    ov1.x += c * nV1[k].x; ov1.y += c * nV1[k].y; ov1.z += c * nV1[k].z; ov1.w += c * nV1[k].w;
  }
  *(float4*)(oS + row * DIM + d0) = os0;
  *(float4*)(oS + row * DIM + d0 + 4) = os1;
  *(float4*)(oV + row * DIM + d0) = ov0;
  *(float4*)(oV + row * DIM + d0 + 4) = ov1;
  *(bf16x8*)(oSb + row * DIM + d0) = pack8(os0, os1);
}

// =========== MFMA NT GEMM + fused per-row top-4 candidate epilogue ===========
// A: bf16 [B][Mpad][512], Bm: bf16 [B][Npad][512]
// cand: [B][Mpad][Npad/64][4] float2 (val, col-as-int); no score matrix written.
__global__ __launch_bounds__(256) void k_mfma_topk(const __bf16* __restrict__ A,
                                                   const __bf16* __restrict__ Bm,
                                                   float2* __restrict__ cand,
                                                   int Mpad, int Npad, int Ntrue) {
  __shared__ __align__(1024) char lds[32768];
  const int tid = threadIdx.x;
  const int wid = tid >> 6, lane = tid & 63;
  const int b = blockIdx.z;
  const long m0 = (long)blockIdx.y * 128;
  const long n0 = (long)blockIdx.x * 128;
  const char* Ab = (const char*)(A + ((long)b * Mpad + m0) * DIM);
  const char* Bb = (const char*)(Bm + ((long)b * Npad + n0) * DIM);
  const int mw = (wid >> 1) * 64, nw = (wid & 1) * 64;

  int srow[2], scol[2], dofs[2];
#pragma unroll
  for (int is = 0; is < 2; ++is) {
    int d = is * 4096 + wid * 1024 + lane * 16;
    int s = d ^ (((d >> 8) & 3) << 4);
    srow[is] = s >> 6;
    scol[is] = s & 63;
    dofs[is] = is * 4096 + wid * 1024;
  }
  int aoff[4], boff[4];
#pragma unroll
  for (int f = 0; f < 4; ++f) {
    int rowA = mw + f * 16 + (lane & 15);
    int byA = rowA * 64 + (lane >> 4) * 16;
    aoff[f] = byA ^ (((byA >> 8) & 3) << 4);
    int rowB = nw + f * 16 + (lane & 15);
    int byB = rowB * 64 + (lane >> 4) * 16;
    boff[f] = (byB ^ (((byB >> 8) & 3) << 4)) + 8192;
  }
  auto stage = [&](int buf, int k0) {
#pragma unroll
    for (int is = 0; is < 2; ++is) {
      gload16(Ab + (long)srow[is] * (DIM * 2) + k0 * 2 + scol[is], lds + buf * 16384 + dofs[is]);
      gload16(Bb + (long)srow[is] * (DIM * 2) + k0 * 2 + scol[is], lds + buf * 16384 + 8192 + dofs[is]);
    }
  };

  f32x4 acc[4][4] = {};
  stage(0, 0);
  asm volatile("s_waitcnt vmcnt(0)" ::: "memory");
  __syncthreads();
  int cur = 0;
  for (int k0 = 0; k0 < DIM; k0 += 32) {
    const bool more = (k0 + 32 < DIM);
    if (more) stage(cur ^ 1, k0 + 32);
    const char* base = lds + cur * 16384;
    bf16x8 af[4], bf[4];
#pragma unroll
    for (int f = 0; f < 4; ++f) {
      af[f] = *(const bf16x8*)(base + aoff[f]);
      bf[f] = *(const bf16x8*)(base + boff[f]);
    }
#pragma unroll
    for (int i = 0; i < 4; ++i)
#pragma unroll
      for (int j = 0; j < 4; ++j)
        acc[i][j] = __builtin_amdgcn_mfma_f32_16x16x32_bf16(af[i], bf[j], acc[i][j], 0, 0, 0);
    if (more) {
      asm volatile("s_waitcnt vmcnt(0)" ::: "memory");
      __syncthreads();
      cur ^= 1;
    }
  }

  // ---- epilogue: per-row top-4 of this wave's 64 cols (16-lane group reduce) ----
  const int NHB = Npad >> 6;
  const int lc = lane & 15;
  const int hb = (int)(n0 >> 6) + (nw >> 6);  // global 64-col half index
#pragma unroll
  for (int i = 0; i < 4; ++i) {
#pragma unroll
    for (int r = 0; r < 4; ++r) {
      float v0 = NEG_INF, v1 = NEG_INF, v2 = NEG_INF, v3 = NEG_INF;
      int i0 = 0x7fffffff, i1 = 0x7fffffff, i2 = 0x7fffffff, i3 = 0x7fffffff;
#pragma unroll
      for (int j = 0; j < 4; ++j) {  // ascending col order -> jax tie-break
        int col = (int)n0 + nw + j * 16 + lc;
        float x = (col < Ntrue) ? acc[i][j][r] : NEG_INF;
        ins4(x, col, v0, v1, v2, v3, i0, i1, i2, i3);
      }
      int ptr = 0;
      float2 out[4];
#pragma unroll
      for (int k = 0; k < 4; ++k) {
        float cv = (ptr == 0) ? v0 : (ptr == 1) ? v1 : (ptr == 2) ? v2 : (ptr == 3) ? v3 : NEG_INF;
        int ci = (ptr == 0) ? i0 : (ptr == 1) ? i1 : (ptr == 2) ? i2 : (ptr == 3) ? i3 : 0x7fffffff;
        float bv = cv;
        int bi = ci;
#pragma unroll
        for (int off = 1; off <= 8; off <<= 1) {  // xor<16: stays in 16-lane group
          float ov = __shfl_xor(bv, off, 64);
          int oi = __shfl_xor(bi, off, 64);
          if (ov > bv || (ov == bv && oi < bi)) { bv = ov; bi = oi; }
        }
        out[k] = make_float2(bv, __int_as_float(bi));
        if (bi == ci) ptr++;
      }
      if (lc == 0) {
        int row = mw + i * 16 + (lane >> 4) * 4 + r;
        float2* cp = cand + (((long)b * Mpad + m0 + row) * NHB + hb) * 4;
        *(float4*)(cp) = make_float4(out[0].x, out[0].y, out[1].x, out[1].y);
        *(float4*)(cp + 2) = make_float4(out[2].x, out[2].y, out[3].x, out[3].y);
      }
    }
  }
}

// ---------------- MFMA NT GEMM storing C (readout only) ----------------
__global__ __launch_bounds__(256) void k_mfma_nt(const __bf16* __restrict__ A,
                                                 const __bf16* __restrict__ Bm,
                                                 float* __restrict__ C,
                                                 const float* __restrict__ bias,
                                                 int Mpad, int Npad, int ldc) {
  __shared__ __align__(1024) char lds[32768];
  const int tid = threadIdx.x;
  const int wid = tid >> 6, lane = tid & 63;
  const int b = blockIdx.z;
  const long m0 = (long)blockIdx.x * 128;  // m-fastest for B-panel L2 reuse
  const long n0 = (long)blockIdx.y * 128;
  const char* Ab = (const char*)(A + ((long)b * Mpad + m0) * DIM);
  const char* Bb = (const char*)(Bm + ((long)b * Npad + n0) * DIM);
  const int mw = (wid >> 1) * 64, nw = (wid & 1) * 64;

  int srow[2], scol[2], dofs[2];
#pragma unroll
  for (int is = 0; is < 2; ++is) {
    int d = is * 4096 + wid * 1024 + lane * 16;
    int s = d ^ (((d >> 8) & 3) << 4);
    srow[is] = s >> 6;
    scol[is] = s & 63;
    dofs[is] = is * 4096 + wid * 1024;
  }
  int aoff[4], boff[4];
#pragma unroll
  for (int f = 0; f < 4; ++f) {
    int rowA = mw + f * 16 + (lane & 15);
    int byA = rowA * 64 + (lane >> 4) * 16;
    aoff[f] = byA ^ (((byA >> 8) & 3) << 4);
    int rowB = nw + f * 16 + (lane & 15);
    int byB = rowB * 64 + (lane >> 4) * 16;
    boff[f] = (byB ^ (((byB >> 8) & 3) << 4)) + 8192;
  }
  auto stage = [&](int buf, int k0) {
#pragma unroll
    for (int is = 0; is < 2; ++is) {
      gload16(Ab + (long)srow[is] * (DIM * 2) + k0 * 2 + scol[is], lds + buf * 16384 + dofs[is]);
      gload16(Bb + (long)srow[is] * (DIM * 2) + k0 * 2 + scol[is], lds + buf * 16384 + 8192 + dofs[is]);
    }
  };

  f32x4 acc[4][4] = {};
  stage(0, 0);
  asm volatile("s_waitcnt vmcnt(0)" ::: "memory");
  __syncthreads();
  int cur = 0;
  for (int k0 = 0; k0 < DIM; k0 += 32) {
    const bool more = (k0 + 32 < DIM);
    if (more) stage(cur ^ 1, k0 + 32);
    const char* base = lds + cur * 16384;
    bf16x8 af[4], bf[4];
#pragma unroll
    for (int f = 0; f < 4; ++f) {
      af[f] = *(const bf16x8*)(base + aoff[f]);
      bf[f] = *(const bf16x8*)(base + boff[f]);
    }
#pragma unroll
    for (int i = 0; i < 4; ++i)
#pragma unroll
      for (int j = 0; j < 4; ++j)
        acc[i][j] = __builtin_amdgcn_mfma_f32_16x16x32_bf16(af[i], bf[j], acc[i][j], 0, 0, 0);
    if (more) {
      asm volatile("s_waitcnt vmcnt(0)" ::: "memory");
      __syncthreads();
      cur ^= 1;
    }
  }
  float* Cb = C + ((long)b * Mpad + m0) * ldc + n0;
  float bv[4];
#pragma unroll
  for (int j = 0; j < 4; ++j) bv[j] = bias[n0 + nw + j * 16 + (lane & 15)];
#pragma unroll
  for (int i = 0; i < 4; ++i) {
    int mrow = mw + i * 16 + (lane >> 4) * 4;
#pragma unroll
    for (int r = 0; r < 4; ++r) {
      long moff = (long)(mrow + r) * ldc;
#pragma unroll
      for (int j = 0; j < 4; ++j) {
        int ncol = nw + j * 16 + (lane & 15);
        __builtin_nontemporal_store(acc[i][j][r] + bv[j], &Cb[moff + ncol]);
      }
    }
  }
}

// ------- merge candidates -> global top-4 + softmax + gather + update (+mirror) -------
__global__ __launch_bounds__(256) void k_topk_merge_update(
    const float2* __restrict__ cand, int CStride, int rowOff, int NHB,
    const float* __restrict__ srcS, const float* __restrict__ srcV,
    const float* __restrict__ baseS, const float* __restrict__ baseV,
    float* __restrict__ outS, float* __restrict__ outV,
    __bf16* __restrict__ outSb, int MpadMir,
    int M, int N, float scale) {
  int wid = threadIdx.x >> 6, lane = threadIdx.x & 63;
  long row = (long)blockIdx.x * 4 + wid;
  long total = (long)NB * M;
  if (row >= total) return;
  int b = (int)(row / M);
  int m = (int)(row - (long)b * M);
  const float2* cp = cand + ((long)b * CStride + rowOff + m) * NHB * 4;
  float v0 = NEG_INF, v1 = NEG_INF, v2 = NEG_INF, v3 = NEG_INF;
  int i0 = 0x7fffffff, i1 = 0x7fffffff, i2 = 0x7fffffff, i3 = 0x7fffffff;
  int tot = NHB * 4;
  for (int p = lane; p < tot; p += 64) {  // ascending p == ascending col for equal vals
    float2 c = cp[p];
    ins4(c.x, __float_as_int(c.y), v0, v1, v2, v3, i0, i1, i2, i3);
  }
  int ptr = 0;
  float rv[4];
  int ri[4];
#pragma unroll
  for (int r = 0; r < 4; ++r) {
    float cv = (ptr == 0) ? v0 : (ptr == 1) ? v1 : (ptr == 2) ? v2 : (ptr == 3) ? v3 : NEG_INF;
    int ci = (ptr == 0) ? i0 : (ptr == 1) ? i1 : (ptr == 2) ? i2 : (ptr == 3) ? i3 : 0x7fffffff;
    float bv = cv;
    int bi = ci;
#pragma unroll
    for (int off = 32; off; off >>= 1) {
      float ov = __shfl_xor(bv, off, 64);
      int oi = __shfl_xor(bi, off, 64);
      if (ov > bv || (ov == bv && oi < bi)) { bv = ov; bi = oi; }
    }
    rv[r] = bv;
    ri[r] = bi;
    if (bi == ci) ptr++;
  }
  float p0 = 1.f, p1 = expf(rv[1] - rv[0]), p2 = expf(rv[2] - rv[0]), p3 = expf(rv[3] - rv[0]);
  float invZ = 1.f / (p0 + p1 + p2 + p3);
  p0 *= invZ; p1 *= invZ; p2 *= invZ; p3 *= invZ;
  int d0 = lane * 8;
  long sb = (long)b * N;
  const float* gs0 = srcS + (sb + ri[0]) * DIM + d0;
  const float* gs1 = srcS + (sb + ri[1]) * DIM + d0;
  const float* gs2 = srcS + (sb + ri[2]) * DIM + d0;
  const float* gs3 = srcS + (sb + ri[3]) * DIM + d0;
  const float* gv0 = srcV + (sb + ri[0]) * DIM + d0;
  const float* gv1 = srcV + (sb + ri[1]) * DIM + d0;
  const float* gv2 = srcV + (sb + ri[2]) * DIM + d0;
  const float* gv3 = srcV + (sb + ri[3]) * DIM + d0;
  long ro = row * DIM + d0;
  float4 osv[2];
#pragma unroll
  for (int h = 0; h < 2; ++h) {
    float4 x0 = *(const float4*)(gs0 + h * 4);
    float4 x1 = *(const float4*)(gs1 + h * 4);
    float4 x2 = *(const float4*)(gs2 + h * 4);
    float4 x3 = *(const float4*)(gs3 + h * 4);
    float4 o = *(const float4*)(baseS + ro + h * 4);
    o.x += scale * (p0 * x0.x + p1 * x1.x + p2 * x2.x + p3 * x3.x);
    o.y += scale * (p0 * x0.y + p1 * x1.y + p2 * x2.y + p3 * x3.y);
    o.z += scale * (p0 * x0.z + p1 * x1.z + p2 * x2.z + p3 * x3.z);
    o.w += scale * (p0 * x0.w + p1 * x1.w + p2 * x2.w + p3 * x3.w);
    *(float4*)(outS + ro + h * 4) = o;
    osv[h] = o;
    float4 y0 = *(const float4*)(gv0 + h * 4);
    float4 y1 = *(const float4*)(gv1 + h * 4);
    float4 y2 = *(const float4*)(gv2 + h * 4);
    float4 y3 = *(const float4*)(gv3 + h * 4);
    float4 q = *(const float4*)(baseV + ro + h * 4);
    q.x += scale * (p0 * y0.x + p1 * y1.x + p2 * y2.x + p3 * y3.x);
    q.y += scale * (p0 * y0.y + p1 * y1.y + p2 * y2.y + p3 * y3.y);
    q.z += scale * (p0 * y0.z + p1 * y1.z + p2 * y2.z + p3 * y3.z);
    q.w += scale * (p0 * y0.w + p1 * y1.w + p2 * y2.w + p3 * y3.w);
    *(float4*)(outV + ro + h * 4) = q;
  }
  if (outSb) {
    *(bf16x8*)(outSb + ((long)b * MpadMir + m) * DIM + d0) = pack8(osv[0], osv[1]);
  }
}

// ---------------- stabilize ----------------
__global__ __launch_bounds__(256) void k_stab(float* __restrict__ state,
                                              float* __restrict__ val,
                                              const float* __restrict__ g,
                                              const float* __restrict__ beta, long rows) {
  int wid = threadIdx.x >> 6, lane = threadIdx.x & 63;
  long row = (long)blockIdx.x * 4 + wid;
  if (row >= rows) return;
  int d0 = lane * 8;
  float* ps = state + row * DIM + d0;
  float4 s0 = *(float4*)ps;
  float4 s1 = *(float4*)(ps + 4);
  s0.x = tanhf(s0.x); s0.y = tanhf(s0.y); s0.z = tanhf(s0.z); s0.w = tanhf(s0.w);
  s1.x = tanhf(s1.x); s1.y = tanhf(s1.y); s1.z = tanhf(s1.z); s1.w = tanhf(s1.w);
  *(float4*)ps = s0;
  *(float4*)(ps + 4) = s1;
  float* pv = val + row * DIM + d0;
  float4 x0 = *(float4*)pv;
  float4 x1 = *(float4*)(pv + 4);
  float sum = x0.x + x0.y + x0.z + x0.w + x1.x + x1.y + x1.z + x1.w;
  sum = wave_sum(sum);
  float mu = sum * (1.f / DIM);
  float d[8] = {x0.x - mu, x0.y - mu, x0.z - mu, x0.w - mu,
                x1.x - mu, x1.y - mu, x1.z - mu, x1.w - mu};
  float ss = d[0]*d[0] + d[1]*d[1] + d[2]*d[2] + d[3]*d[3] + d[4]*d[4] + d[5]*d[5] + d[6]*d[6] + d[7]*d[7];
  ss = wave_sum(ss);
  float rs = rsqrtf(ss * (1.f / DIM) + 1e-5f);
  float4 g0 = *(const float4*)(g + d0);
  float4 g1 = *(const float4*)(g + d0 + 4);
  float4 b0 = *(const float4*)(beta + d0);
  float4 b1 = *(const float4*)(beta + d0 + 4);
  x0.x = d[0] * rs * g0.x + b0.x; x0.y = d[1] * rs * g0.y + b0.y;
  x0.z = d[2] * rs * g0.z + b0.z; x0.w = d[3] * rs * g0.w + b0.w;
  x1.x = d[4] * rs * g1.x + b1.x; x1.y = d[5] * rs * g1.y + b1.y;
  x1.z = d[6] * rs * g1.z + b1.z; x1.w = d[7] * rs * g1.w + b1.w;
  *(float4*)pv = x0;
  *(float4*)(pv + 4) = x1;
}

// =======================================================================
extern "C" void kernel_launch(void* const* d_in, const int* in_sizes, int n_in,
                              void* d_out, int out_size, void* d_ws, size_t ws_size,
                              hipStream_t stream) {
  (void)in_sizes; (void)n_in; (void)out_size; (void)ws_size;
  const int* tokens = (const int*)d_in[0];
  const float* embed = (const float*)d_in[1];
  const float* readout_w = (const float*)d_in[2];
  const float* readout_b = (const float*)d_in[3];
  const float* w_s = (const float*)d_in[4];
  const float* w_se = (const float*)d_in[5];
  const float* w_sc = (const float*)d_in[6];
  const float* w_s2e = (const float*)d_in[7];
  const float* w_e2s = (const float*)d_in[8];
  const float* w_s2c = (const float*)d_in[9];
  const float* w_c2s = (const float*)d_in[10];
  const float* ln_s_g = (const float*)d_in[11];
  const float* ln_s_b = (const float*)d_in[12];
  const float* ln_e_g = (const float*)d_in[13];
  const float* ln_e_b = (const float*)d_in[14];
  const float* ln_c_g = (const float*)d_in[15];
  const float* ln_c_b = (const float*)d_in[16];
  const float* pe_e[3] = {(const float*)d_in[17], (const float*)d_in[19], (const float*)d_in[21]};
  const float* pe_c[3] = {(const float*)d_in[18], (const float*)d_in[20], (const float*)d_in[22]};

  static const int NEXP[3] = {2151, 2253, 2458};
  static const int NCMP[3] = {1844, 1639, 1434};
  static const int NEXP_P[3] = {2176, 2304, 2560};
  static const int NCMP_P[3] = {1920, 1664, 1536};
  static const int LAYERS[3] = {2, 2, 1};
  static const float ALPHA[3][3] = {{0.3f, 0.25f, 0.15f}, {0.65f, 0.55f, 0.35f}, {1.0f, 0.9f, 0.8f}};

  const long SZ_S = 2L * SEQ * DIM;
  const long SZ_E = 2L * 2458 * DIM;
  const long SZ_C = 2L * 1844 * DIM;
  float* ws = (float*)d_ws;
  float* sS[2] = {ws, ws + SZ_S}; ws += 2 * SZ_S;
  float* sV[2] = {ws, ws + SZ_S}; ws += 2 * SZ_S;
  float* eS[2] = {ws, ws + SZ_E}; ws += 2 * SZ_E;
  float* eV[2] = {ws, ws + SZ_E}; ws += 2 * SZ_E;
  float* cS[2] = {ws, ws + SZ_C}; ws += 2 * SZ_C;
  float* cV[2] = {ws, ws + SZ_C}; ws += 2 * SZ_C;
  __bf16* bw = (__bf16*)ws;
  __bf16* sb = bw;   bw += 2L * 2048 * DIM;
  __bf16* eb = bw;   bw += 2L * 2560 * DIM;
  __bf16* cb = bw;   bw += 2L * 1920 * DIM;
  __bf16* awb = bw;  bw += 2L * 4096 * DIM;   // combined e+c A panel
  __bf16* valb = bw; bw += 4096L * DIM;
  __bf16* rwT = bw;  bw += 32000L * DIM;
  float2* cand = (float2*)bw;                 // max 2 * 131072 * 4 float2 = 8.4 MB

  auto cdiv = [](long a, long b) { return (int)((a + b - 1) / b); };

  k_embed<<<NB * SEQ, 128, 0, stream>>>(tokens, embed, sS[0], sV[0]);

  int cs = 0, li = 0;
  for (int st = 0; st < 3; ++st) {
    const int Ne = NEXP[st], Nc = NCMP[st];
    const int NeP = NEXP_P[st], NcP = NCMP_P[st];
    const int CR = NeP + NcP;                  // combined rows for s->e|c GEMM
    const float alpha = ALPHA[st][0], bs2b = ALPHA[st][1], bb2s = ALPHA[st][2];
    const float sc_x = 0.15f * bs2b * alpha;
    const float sc_b = 0.2f * alpha;
    const float sc_s = 0.15f * bb2s;
    int ce = 0, cc = 0;
    k_bcast2<<<cdiv((long)NB * NeP, 4), 256, 0, stream>>>(pe_e[st], eS[0], eV[0], eb, Ne, NeP);
    k_bcast2<<<cdiv((long)NB * NcP, 4), 256, 0, stream>>>(pe_c[st], cS[0], cV[0], cb, Nc, NcP);
    for (int l = 0; l < LAYERS[st]; ++l) {
      // 1. window prop
      k_window<<<NB * SEQ / 4, 256, 0, stream>>>(sS[cs], sV[cs], w_s + (long)li * DIM,
                                                 sS[cs ^ 1], sV[cs ^ 1], sb);
      cs ^= 1;
      // 2+3. s -> e and s -> c : ONE GEMM (shared B panel = sb)
      k_cvt_aw<<<cdiv((long)NB * NeP, 4), 256, 0, stream>>>(eS[ce], w_s2e + (long)li * DIM, awb,
                                                            Ne, NeP, 0, CR);
      k_cvt_aw<<<cdiv((long)NB * NcP, 4), 256, 0, stream>>>(cS[cc], w_s2c + (long)li * DIM, awb,
                                                            Nc, NcP, NeP, CR);
      {
        dim3 g(SEQ / 128, CR / 128, NB);
        k_mfma_topk<<<g, 256, 0, stream>>>(awb, sb, cand, CR, SEQ, SEQ);
      }
      k_topk_merge_update<<<cdiv((long)NB * Ne, 4), 256, 0, stream>>>(
          cand, CR, 0, SEQ / 64, sS[cs], sV[cs], eS[ce], eV[ce], eS[ce ^ 1], eV[ce ^ 1],
          eb, NeP, Ne, SEQ, sc_x);
      ce ^= 1;
      k_topk_merge_update<<<cdiv((long)NB * Nc, 4), 256, 0, stream>>>(
          cand, CR, NeP, SEQ / 64, sS[cs], sV[cs], cS[cc], cV[cc], cS[cc ^ 1], cV[cc ^ 1],
          cb, NcP, Nc, SEQ, sc_x);
      cc ^= 1;
      // 4. e self
      k_cvt_aw<<<cdiv((long)NB * NeP, 4), 256, 0, stream>>>(eS[ce], w_se + (long)li * DIM, awb,
                                                            Ne, NeP, 0, NeP);
      {
        dim3 g(NeP / 128, NeP / 128, NB);
        k_mfma_topk<<<g, 256, 0, stream>>>(awb, eb, cand, NeP, NeP, Ne);
      }
      k_topk_merge_update<<<cdiv((long)NB * Ne, 4), 256, 0, stream>>>(
          cand, NeP, 0, NeP / 64, eS[ce], eV[ce], eS[ce], eV[ce], eS[ce ^ 1], eV[ce ^ 1],
          eb, NeP, Ne, Ne, sc_b);
      ce ^= 1;
      // 5. c self
      k_cvt_aw<<<cdiv((long)NB * NcP, 4), 256, 0, stream>>>(cS[cc], w_sc + (long)li * DIM, awb,
                                                            Nc, NcP, 0, NcP);
      {
        dim3 g(NcP / 128, NcP / 128, NB);
        k_mfma_topk<<<g, 256, 0, stream>>>(awb, cb, cand, NcP, NcP, Nc);
      }
      k_topk_merge_update<<<cdiv((long)NB * Nc, 4), 256, 0, stream>>>(
          cand, NcP, 0, NcP / 64, cS[cc], cV[cc], cS[cc], cV[cc], cS[cc ^ 1], cV[cc ^ 1],
          cb, NcP, Nc, Nc, sc_b);
      cc ^= 1;
      // 6a. e -> s
      k_cvt_aw<<<cdiv((long)NB * SEQ, 4), 256, 0, stream>>>(sS[cs], w_e2s + (long)li * DIM, awb,
                                                            SEQ, SEQ, 0, SEQ);
      {
        dim3 g(NeP / 128, SEQ / 128, NB);
        k_mfma_topk<<<g, 256, 0, stream>>>(awb, eb, cand, SEQ, NeP, Ne);
      }
      k_topk_merge_update<<<NB * SEQ / 4, 256, 0, stream>>>(
          cand, SEQ, 0, NeP / 64, eS[ce], eV[ce], sS[cs], sV[cs], sS[cs ^ 1], sV[cs ^ 1],
          nullptr, 0, SEQ, Ne, sc_s);
      // 6b. c -> s (accumulate in place)
      k_cvt_aw<<<cdiv((long)NB * SEQ, 4), 256, 0, stream>>>(sS[cs], w_c2s + (long)li * DIM, awb,
                                                            SEQ, SEQ, 0, SEQ);
      {
        dim3 g(NcP / 128, SEQ / 128, NB);
        k_mfma_topk<<<g, 256, 0, stream>>>(awb, cb, cand, SEQ, NcP, Nc);
      }
      k_topk_merge_update<<<NB * SEQ / 4, 256, 0, stream>>>(
          cand, SEQ, 0, NcP / 64, cS[cc], cV[cc], sS[cs ^ 1], sV[cs ^ 1], sS[cs ^ 1], sV[cs ^ 1],
          nullptr, 0, SEQ, Nc, sc_s);
      cs ^= 1;
      // 7. stabilize
      k_stab<<<NB * SEQ / 4, 256, 0, stream>>>(sS[cs], sV[cs], ln_s_g + (long)li * DIM,
                                               ln_s_b + (long)li * DIM, (long)NB * SEQ);
      k_stab<<<cdiv((long)NB * Ne, 4), 256, 0, stream>>>(eS[ce], eV[ce], ln_e_g + (long)li * DIM,
                                                         ln_e_b + (long)li * DIM, (long)NB * Ne);
      k_stab<<<cdiv((long)NB * Nc, 4), 256, 0, stream>>>(cS[cc], cV[cc], ln_c_g + (long)li * DIM,
                                                         ln_c_b + (long)li * DIM, (long)NB * Nc);
      ++li;
    }
  }
  // readout
  k_cvt_val<<<NB * SEQ / 4, 256, 0, stream>>>(sV[cs], valb);
  {
    dim3 g(1000, 16);
    dim3 blk(32, 8);
    k_transpose_rw<<<g, blk, 0, stream>>>(readout_w, rwT);
  }
  {
    dim3 g((NB * SEQ) / 128, 32000 / 128, 1);
    k_mfma_nt<<<g, 256, 0, stream>>>(valb, rwT, (float*)d_out, readout_b, NB * SEQ, 32000, 32000);
  }
}

// Round 5
// 3682.560 us; speedup vs baseline: 1.0456x; 1.0456x over previous
//
#include <hip/hip_runtime.h>
#include <hip/hip_bf16.h>
#include <math.h>

#define DIM 512
#define SEQ 2048
#define NB 2
#define NEG_INF (-1e30f)

typedef __bf16 bf16x8 __attribute__((ext_vector_type(8)));
typedef float f32x4 __attribute__((ext_vector_type(4)));

static __device__ __forceinline__ float wave_sum(float x) {
#pragma unroll
  for (int off = 32; off; off >>= 1) x += __shfl_xor(x, off, 64);
  return x;
}

static __device__ __forceinline__ bf16x8 pack8(float4 a, float4 b) {
  bf16x8 r;
  r[0] = (__bf16)a.x; r[1] = (__bf16)a.y; r[2] = (__bf16)a.z; r[3] = (__bf16)a.w;
  r[4] = (__bf16)b.x; r[5] = (__bf16)b.y; r[6] = (__bf16)b.z; r[7] = (__bf16)b.w;
  return r;
}

static __device__ __forceinline__ void gload16(const void* g, void* l) {
  __builtin_amdgcn_global_load_lds((const __attribute__((address_space(1))) void*)g,
                                   (__attribute__((address_space(3))) void*)l, 16, 0, 0);
}

// sorted top-4 insert, strict >, earlier-inserted wins ties (callers insert in
// ascending-index order so ties keep the lower index == jax.lax.top_k)
static __device__ __forceinline__ void ins4(float x, int s, float& v0, float& v1, float& v2,
                                            float& v3, int& i0, int& i1, int& i2, int& i3) {
  if (x > v3) {
    if (x > v0) { v3 = v2; i3 = i2; v2 = v1; i2 = i1; v1 = v0; i1 = i0; v0 = x; i0 = s; }
    else if (x > v1) { v3 = v2; i3 = i2; v2 = v1; i2 = i1; v1 = x; i1 = s; }
    else if (x > v2) { v3 = v2; i3 = i2; v2 = x; i2 = s; }
    else { v3 = x; i3 = s; }
  }
}

// ---------------- embed gather ----------------
__global__ __launch_bounds__(128) void k_embed(const int* __restrict__ tok,
                                               const float* __restrict__ emb,
                                               float* __restrict__ sS,
                                               float* __restrict__ sV) {
  long row = blockIdx.x;
  int t = tok[row];
  const float4* src = (const float4*)(emb + (long)t * DIM);
  float4* a = (float4*)(sS + row * DIM);
  float4* b = (float4*)(sV + row * DIM);
  int i = threadIdx.x;
  float4 v = src[i];
  a[i] = v;
  b[i] = v;
}

// ---------------- broadcast pe -> f32 state/val + zero-padded bf16 mirror ----------------
__global__ __launch_bounds__(256) void k_bcast2(const float* __restrict__ pe,
                                                float* __restrict__ s, float* __restrict__ v,
                                                __bf16* __restrict__ mb, int N, int Npad) {
  int wid = threadIdx.x >> 6, lane = threadIdx.x & 63;
  long row = (long)blockIdx.x * 4 + wid;
  if (row >= (long)NB * Npad) return;
  int b = (int)(row / Npad), m = (int)(row % Npad);
  int d0 = lane * 8;
  if (m < N) {
    float4 x0 = *(const float4*)(pe + (long)m * DIM + d0);
    float4 x1 = *(const float4*)(pe + (long)m * DIM + d0 + 4);
    long fo = ((long)b * N + m) * DIM + d0;
    *(float4*)(s + fo) = x0; *(float4*)(s + fo + 4) = x1;
    *(float4*)(v + fo) = x0; *(float4*)(v + fo + 4) = x1;
    *(bf16x8*)(mb + row * DIM + d0) = pack8(x0, x1);
  } else {
    bf16x8 z;
#pragma unroll
    for (int i = 0; i < 8; ++i) z[i] = (__bf16)0.f;
    *(bf16x8*)(mb + row * DIM + d0) = z;
  }
}

// ------- A-side cvt: bf16 out[b*CStride + rowOff + m][:] = state*w (pad rows = 0) -------
__global__ __launch_bounds__(256) void k_cvt_aw(const float* __restrict__ in,
                                                const float* __restrict__ w,
                                                __bf16* __restrict__ out, int M, int Mpad,
                                                int rowOff, int CStride) {
  int wid = threadIdx.x >> 6, lane = threadIdx.x & 63;
  long row = (long)blockIdx.x * 4 + wid;
  if (row >= (long)NB * Mpad) return;
  int b = (int)(row / Mpad), m = (int)(row % Mpad);
  int d0 = lane * 8;
  long oo = ((long)b * CStride + rowOff + m) * DIM + d0;
  if (m < M) {
    long fo = ((long)b * M + m) * DIM + d0;
    float4 x0 = *(const float4*)(in + fo);
    float4 x1 = *(const float4*)(in + fo + 4);
    float4 w0 = *(const float4*)(w + d0);
    float4 w1 = *(const float4*)(w + d0 + 4);
    x0.x *= w0.x; x0.y *= w0.y; x0.z *= w0.z; x0.w *= w0.w;
    x1.x *= w1.x; x1.y *= w1.y; x1.z *= w1.z; x1.w *= w1.w;
    *(bf16x8*)(out + oo) = pack8(x0, x1);
  } else {
    bf16x8 z;
#pragma unroll
    for (int i = 0; i < 8; ++i) z[i] = (__bf16)0.f;
    *(bf16x8*)(out + oo) = z;
  }
}

// ---------------- plain f32->bf16 rows (readout A) ----------------
__global__ __launch_bounds__(256) void k_cvt_val(const float* __restrict__ in,
                                                 __bf16* __restrict__ out) {
  int wid = threadIdx.x >> 6, lane = threadIdx.x & 63;
  long row = (long)blockIdx.x * 4 + wid;
  int d0 = lane * 8;
  float4 x0 = *(const float4*)(in + row * DIM + d0);
  float4 x1 = *(const float4*)(in + row * DIM + d0 + 4);
  *(bf16x8*)(out + row * DIM + d0) = pack8(x0, x1);
}

// ---------------- readout_w transpose+cvt: f32[512][32000] -> bf16[32000][512] ----------------
__global__ __launch_bounds__(256) void k_transpose_rw(const float* __restrict__ in,
                                                      __bf16* __restrict__ out) {
  __shared__ float t[32][33];
  int tx = threadIdx.x, ty = threadIdx.y;
  int n0 = blockIdx.x * 32, k0 = blockIdx.y * 32;
#pragma unroll
  for (int i = 0; i < 4; ++i)
    t[ty + i * 8][tx] = in[(long)(k0 + ty + i * 8) * 32000 + n0 + tx];
  __syncthreads();
#pragma unroll
  for (int i = 0; i < 4; ++i)
    out[(long)(n0 + ty + i * 8) * DIM + k0 + tx] = (__bf16)t[tx][ty + i * 8];
}

// ---------------- causal window-4 propagation ----------------
__global__ __launch_bounds__(256) void k_window(const float* __restrict__ sS,
                                                const float* __restrict__ sV,
                                                const float* __restrict__ w,
                                                float* __restrict__ oS,
                                                float* __restrict__ oV,
                                                __bf16* __restrict__ oSb) {
  int wid = threadIdx.x >> 6, lane = threadIdx.x & 63;
  long row = (long)blockIdx.x * 4 + wid;
  int i = (int)(row & (SEQ - 1));
  int d0 = lane * 8;
  const float* ps = sS + row * DIM + d0;
  const float* pv = sV + row * DIM + d0;
  float4 s0 = *(const float4*)ps;
  float4 s1 = *(const float4*)(ps + 4);
  float4 w0 = *(const float4*)(w + d0);
  float4 w1 = *(const float4*)(w + d0 + 4);
  float4 aw0 = make_float4(s0.x * w0.x, s0.y * w0.y, s0.z * w0.z, s0.w * w0.w);
  float4 aw1 = make_float4(s1.x * w1.x, s1.y * w1.y, s1.z * w1.z, s1.w * w1.w);
  float4 nS0[4], nS1[4], nV0[4], nV1[4];
  float sc[4];
#pragma unroll
  for (int k = 0; k < 4; ++k) {
    bool valid = (i >= k + 1);
    const float* qs = ps - (long)(k + 1) * DIM;
    const float* qv = pv - (long)(k + 1) * DIM;
    if (valid) {
      nS0[k] = *(const float4*)qs;
      nS1[k] = *(const float4*)(qs + 4);
      nV0[k] = *(const float4*)qv;
      nV1[k] = *(const float4*)(qv + 4);
    } else {
      nS0[k] = make_float4(0.f, 0.f, 0.f, 0.f);
      nS1[k] = nS0[k]; nV0[k] = nS0[k]; nV1[k] = nS0[k];
    }
    sc[k] = aw0.x * nS0[k].x + aw0.y * nS0[k].y + aw0.z * nS0[k].z + aw0.w * nS0[k].w +
            aw1.x * nS1[k].x + aw1.y * nS1[k].y + aw1.z * nS1[k].z + aw1.w * nS1[k].w;
  }
#pragma unroll
  for (int k = 0; k < 4; ++k) sc[k] = wave_sum(sc[k]);
  float m = NEG_INF;
#pragma unroll
  for (int k = 0; k < 4; ++k)
    if (i >= k + 1 && sc[k] > m) m = sc[k];
  float p[4];
  float Z = 0.f;
#pragma unroll
  for (int k = 0; k < 4; ++k) {
    p[k] = (i >= k + 1) ? expf(sc[k] - m) : 0.f;
    Z += p[k];
  }
  float invZ = (Z > 0.f) ? (1.f / Z) : 0.f;
  float4 v0 = *(const float4*)pv;
  float4 v1 = *(const float4*)(pv + 4);
  float4 os0 = s0, os1 = s1, ov0 = v0, ov1 = v1;
#pragma unroll
  for (int k = 0; k < 4; ++k) {
    float c = 0.25f * p[k] * invZ;
    os0.x += c * nS0[k].x; os0.y += c * nS0[k].y; os0.z += c * nS0[k].z; os0.w += c * nS0[k].w;
    os1.x += c * nS1[k].x; os1.y += c * nS1[k].y; os1.z += c * nS1[k].z; os1.w += c * nS1[k].w;
    ov0.x += c * nV0[k].x; ov0.y += c * nV0[k].y; ov0.z += c * nV0[k].z; ov0.w += c * nV0[k].w;
    ov1.x += c * nV1[k].x; ov1.y += c * nV1[k].y; ov1.z += c * nV1[k].z; ov1.w += c * nV1[k].w;
  }
  *(float4*)(oS + row * DIM + d0) = os0;
  *(float4*)(oS + row * DIM + d0 + 4) = os1;
  *(float4*)(oV + row * DIM + d0) = ov0;
  *(float4*)(oV + row * DIM + d0 + 4) = ov1;
  *(bf16x8*)(oSb + row * DIM + d0) = pack8(os0, os1);
}

// ---------------- MFMA NT GEMM, 2-phase double-buffered LDS ----------------
// A: bf16 [B][Mpad][512], Bm: bf16 [B][Npad][512], C: f32 [B][Mpad][ldc]
// swapxy=1: blockIdx.x indexes M (m-fastest, for B-panel L2 reuse on readout)
template <bool NT>
__global__ __launch_bounds__(256) void k_mfma_nt(const __bf16* __restrict__ A,
                                                 const __bf16* __restrict__ Bm,
                                                 float* __restrict__ C,
                                                 const float* __restrict__ bias,
                                                 int Mpad, int Npad, int ldc, int swapxy) {
  __shared__ __align__(1024) char lds[32768];  // 2 bufs x (A 8KB | B 8KB)
  const int tid = threadIdx.x;
  const int wid = tid >> 6, lane = tid & 63;
  const int b = blockIdx.z;
  const long m0 = (swapxy ? (long)blockIdx.x : (long)blockIdx.y) * 128;
  const long n0 = (swapxy ? (long)blockIdx.y : (long)blockIdx.x) * 128;
  const char* Ab = (const char*)(A + ((long)b * Mpad + m0) * DIM);
  const char* Bb = (const char*)(Bm + ((long)b * Npad + n0) * DIM);
  const int mw = (wid >> 1) * 64, nw = (wid & 1) * 64;

  int srow[2], scol[2], dofs[2];
#pragma unroll
  for (int is = 0; is < 2; ++is) {
    int d = is * 4096 + wid * 1024 + lane * 16;
    int s = d ^ (((d >> 8) & 3) << 4);
    srow[is] = s >> 6;
    scol[is] = s & 63;
    dofs[is] = is * 4096 + wid * 1024;
  }
  int aoff[4], boff[4];
#pragma unroll
  for (int f = 0; f < 4; ++f) {
    int rowA = mw + f * 16 + (lane & 15);
    int byA = rowA * 64 + (lane >> 4) * 16;
    aoff[f] = byA ^ (((byA >> 8) & 3) << 4);
    int rowB = nw + f * 16 + (lane & 15);
    int byB = rowB * 64 + (lane >> 4) * 16;
    boff[f] = (byB ^ (((byB >> 8) & 3) << 4)) + 8192;
  }
  auto stage = [&](int buf, int k0) {
#pragma unroll
    for (int is = 0; is < 2; ++is) {
      gload16(Ab + (long)srow[is] * (DIM * 2) + k0 * 2 + scol[is], lds + buf * 16384 + dofs[is]);
      gload16(Bb + (long)srow[is] * (DIM * 2) + k0 * 2 + scol[is], lds + buf * 16384 + 8192 + dofs[is]);
    }
  };

  f32x4 acc[4][4] = {};
  stage(0, 0);
  asm volatile("s_waitcnt vmcnt(0)" ::: "memory");
  __syncthreads();
  int cur = 0;
  for (int k0 = 0; k0 < DIM; k0 += 32) {
    const bool more = (k0 + 32 < DIM);
    if (more) stage(cur ^ 1, k0 + 32);  // prefetch next tile, in flight during MFMA
    const char* base = lds + cur * 16384;
    bf16x8 af[4], bf[4];
#pragma unroll
    for (int f = 0; f < 4; ++f) {
      af[f] = *(const bf16x8*)(base + aoff[f]);
      bf[f] = *(const bf16x8*)(base + boff[f]);
    }
#pragma unroll
    for (int i = 0; i < 4; ++i)
#pragma unroll
      for (int j = 0; j < 4; ++j)
        acc[i][j] = __builtin_amdgcn_mfma_f32_16x16x32_bf16(af[i], bf[j], acc[i][j], 0, 0, 0);
    if (more) {
      asm volatile("s_waitcnt vmcnt(0)" ::: "memory");
      __syncthreads();
      cur ^= 1;
    }
  }
  float* Cb = C + ((long)b * Mpad + m0) * ldc + n0;
  float bv[4] = {0.f, 0.f, 0.f, 0.f};
  if (bias) {
#pragma unroll
    for (int j = 0; j < 4; ++j) bv[j] = bias[n0 + nw + j * 16 + (lane & 15)];
  }
#pragma unroll
  for (int i = 0; i < 4; ++i) {
    int mrow = mw + i * 16 + (lane >> 4) * 4;
#pragma unroll
    for (int r = 0; r < 4; ++r) {
      long moff = (long)(mrow + r) * ldc;
#pragma unroll
      for (int j = 0; j < 4; ++j) {
        int ncol = nw + j * 16 + (lane & 15);
        float v = acc[i][j][r] + bv[j];
        if (NT)
          __builtin_nontemporal_store(v, &Cb[moff + ncol]);
        else
          Cb[moff + ncol] = v;
      }
    }
  }
}

// ---------------- fused top-4 + softmax + gather + update (32B/lane scan) ----------------
__global__ __launch_bounds__(256) void k_topk_update(
    const float* __restrict__ scores, int Mpad, int rowOff, int ldc,
    const float* __restrict__ srcS, const float* __restrict__ srcV,
    const float* __restrict__ baseS, const float* __restrict__ baseV,
    float* __restrict__ outS, float* __restrict__ outV,
    __bf16* __restrict__ outSb, int MpadMir,
    int M, int N, float scale) {
  int wid = threadIdx.x >> 6, lane = threadIdx.x & 63;
  long row = (long)blockIdx.x * 4 + wid;
  long total = (long)NB * M;
  if (row >= total) return;
  int b = (int)(row / M);
  int m = (int)(row - (long)b * M);
  const float* sc = scores + ((long)b * Mpad + rowOff + m) * ldc;
  float v0 = NEG_INF, v1 = NEG_INF, v2 = NEG_INF, v3 = NEG_INF;
  int i0 = 0x7fffffff, i1 = 0x7fffffff, i2 = 0x7fffffff, i3 = 0x7fffffff;
  for (int s8 = lane * 8; s8 < ldc; s8 += 512) {
    float4 x = *(const float4*)(sc + s8);
    float4 y = *(const float4*)(sc + s8 + 4);
    if (s8 + 7 >= N) {  // mask pad cols (pad B rows give 0-scores)
      if (s8 + 0 >= N) x.x = NEG_INF;
      if (s8 + 1 >= N) x.y = NEG_INF;
      if (s8 + 2 >= N) x.z = NEG_INF;
      if (s8 + 3 >= N) x.w = NEG_INF;
      if (s8 + 4 >= N) y.x = NEG_INF;
      if (s8 + 5 >= N) y.y = NEG_INF;
      if (s8 + 6 >= N) y.z = NEG_INF;
      if (s8 + 7 >= N) y.w = NEG_INF;
    }
    float mx = fmaxf(fmaxf(fmaxf(x.x, x.y), fmaxf(x.z, x.w)),
                     fmaxf(fmaxf(y.x, y.y), fmaxf(y.z, y.w)));
    if (mx > v3) {  // ascending col order inside -> jax tie-break preserved
      ins4(x.x, s8 + 0, v0, v1, v2, v3, i0, i1, i2, i3);
      ins4(x.y, s8 + 1, v0, v1, v2, v3, i0, i1, i2, i3);
      ins4(x.z, s8 + 2, v0, v1, v2, v3, i0, i1, i2, i3);
      ins4(x.w, s8 + 3, v0, v1, v2, v3, i0, i1, i2, i3);
      ins4(y.x, s8 + 4, v0, v1, v2, v3, i0, i1, i2, i3);
      ins4(y.y, s8 + 5, v0, v1, v2, v3, i0, i1, i2, i3);
      ins4(y.z, s8 + 6, v0, v1, v2, v3, i0, i1, i2, i3);
      ins4(y.w, s8 + 7, v0, v1, v2, v3, i0, i1, i2, i3);
    }
  }
  int ptr = 0;
  float rv[4];
  int ri[4];
#pragma unroll
  for (int r = 0; r < 4; ++r) {
    float cv = (ptr == 0) ? v0 : (ptr == 1) ? v1 : (ptr == 2) ? v2 : (ptr == 3) ? v3 : NEG_INF;
    int ci = (ptr == 0) ? i0 : (ptr == 1) ? i1 : (ptr == 2) ? i2 : (ptr == 3) ? i3 : 0x7fffffff;
    float bv = cv;
    int bi = ci;
#pragma unroll
    for (int off = 32; off; off >>= 1) {
      float ov = __shfl_xor(bv, off, 64);
      int oi = __shfl_xor(bi, off, 64);
      if (ov > bv || (ov == bv && oi < bi)) { bv = ov; bi = oi; }
    }
    rv[r] = bv;
    ri[r] = bi;
    if (bi == ci) ptr++;
  }
  float p0 = 1.f, p1 = expf(rv[1] - rv[0]), p2 = expf(rv[2] - rv[0]), p3 = expf(rv[3] - rv[0]);
  float invZ = 1.f / (p0 + p1 + p2 + p3);
  p0 *= invZ; p1 *= invZ; p2 *= invZ; p3 *= invZ;
  int d0 = lane * 8;
  long sb = (long)b * N;
  const float* gs0 = srcS + (sb + ri[0]) * DIM + d0;
  const float* gs1 = srcS + (sb + ri[1]) * DIM + d0;
  const float* gs2 = srcS + (sb + ri[2]) * DIM + d0;
  const float* gs3 = srcS + (sb + ri[3]) * DIM + d0;
  const float* gv0 = srcV + (sb + ri[0]) * DIM + d0;
  const float* gv1 = srcV + (sb + ri[1]) * DIM + d0;
  const float* gv2 = srcV + (sb + ri[2]) * DIM + d0;
  const float* gv3 = srcV + (sb + ri[3]) * DIM + d0;
  long ro = row * DIM + d0;
  float4 osv[2];
#pragma unroll
  for (int h = 0; h < 2; ++h) {
    float4 x0 = *(const float4*)(gs0 + h * 4);
    float4 x1 = *(const float4*)(gs1 + h * 4);
    float4 x2 = *(const float4*)(gs2 + h * 4);
    float4 x3 = *(const float4*)(gs3 + h * 4);
    float4 o = *(const float4*)(baseS + ro + h * 4);
    o.x += scale * (p0 * x0.x + p1 * x1.x + p2 * x2.x + p3 * x3.x);
    o.y += scale * (p0 * x0.y + p1 * x1.y + p2 * x2.y + p3 * x3.y);
    o.z += scale * (p0 * x0.z + p1 * x1.z + p2 * x2.z + p3 * x3.z);
    o.w += scale * (p0 * x0.w + p1 * x1.w + p2 * x2.w + p3 * x3.w);
    *(float4*)(outS + ro + h * 4) = o;
    osv[h] = o;
    float4 y0 = *(const float4*)(gv0 + h * 4);
    float4 y1 = *(const float4*)(gv1 + h * 4);
    float4 y2 = *(const float4*)(gv2 + h * 4);
    float4 y3 = *(const float4*)(gv3 + h * 4);
    float4 q = *(const float4*)(baseV + ro + h * 4);
    q.x += scale * (p0 * y0.x + p1 * y1.x + p2 * y2.x + p3 * y3.x);
    q.y += scale * (p0 * y0.y + p1 * y1.y + p2 * y2.y + p3 * y3.y);
    q.z += scale * (p0 * y0.z + p1 * y1.z + p2 * y2.z + p3 * y3.z);
    q.w += scale * (p0 * y0.w + p1 * y1.w + p2 * y2.w + p3 * y3.w);
    *(float4*)(outV + ro + h * 4) = q;
  }
  if (outSb) {
    *(bf16x8*)(outSb + ((long)b * MpadMir + m) * DIM + d0) = pack8(osv[0], osv[1]);
  }
}

// ---------------- stabilize ----------------
__global__ __launch_bounds__(256) void k_stab(float* __restrict__ state,
                                              float* __restrict__ val,
                                              const float* __restrict__ g,
                                              const float* __restrict__ beta, long rows) {
  int wid = threadIdx.x >> 6, lane = threadIdx.x & 63;
  long row = (long)blockIdx.x * 4 + wid;
  if (row >= rows) return;
  int d0 = lane * 8;
  float* ps = state + row * DIM + d0;
  float4 s0 = *(float4*)ps;
  float4 s1 = *(float4*)(ps + 4);
  s0.x = tanhf(s0.x); s0.y = tanhf(s0.y); s0.z = tanhf(s0.z); s0.w = tanhf(s0.w);
  s1.x = tanhf(s1.x); s1.y = tanhf(s1.y); s1.z = tanhf(s1.z); s1.w = tanhf(s1.w);
  *(float4*)ps = s0;
  *(float4*)(ps + 4) = s1;
  float* pv = val + row * DIM + d0;
  float4 x0 = *(float4*)pv;
  float4 x1 = *(float4*)(pv + 4);
  float sum = x0.x + x0.y + x0.z + x0.w + x1.x + x1.y + x1.z + x1.w;
  sum = wave_sum(sum);
  float mu = sum * (1.f / DIM);
  float d[8] = {x0.x - mu, x0.y - mu, x0.z - mu, x0.w - mu,
                x1.x - mu, x1.y - mu, x1.z - mu, x1.w - mu};
  float ss = d[0]*d[0] + d[1]*d[1] + d[2]*d[2] + d[3]*d[3] + d[4]*d[4] + d[5]*d[5] + d[6]*d[6] + d[7]*d[7];
  ss = wave_sum(ss);
  float rs = rsqrtf(ss * (1.f / DIM) + 1e-5f);
  float4 g0 = *(const float4*)(g + d0);
  float4 g1 = *(const float4*)(g + d0 + 4);
  float4 b0 = *(const float4*)(beta + d0);
  float4 b1 = *(const float4*)(beta + d0 + 4);
  x0.x = d[0] * rs * g0.x + b0.x; x0.y = d[1] * rs * g0.y + b0.y;
  x0.z = d[2] * rs * g0.z + b0.z; x0.w = d[3] * rs * g0.w + b0.w;
  x1.x = d[4] * rs * g1.x + b1.x; x1.y = d[5] * rs * g1.y + b1.y;
  x1.z = d[6] * rs * g1.z + b1.z; x1.w = d[7] * rs * g1.w + b1.w;
  *(float4*)pv = x0;
  *(float4*)(pv + 4) = x1;
}

// =======================================================================
extern "C" void kernel_launch(void* const* d_in, const int* in_sizes, int n_in,
                              void* d_out, int out_size, void* d_ws, size_t ws_size,
                              hipStream_t stream) {
  (void)in_sizes; (void)n_in; (void)out_size; (void)ws_size;
  const int* tokens = (const int*)d_in[0];
  const float* embed = (const float*)d_in[1];
  const float* readout_w = (const float*)d_in[2];
  const float* readout_b = (const float*)d_in[3];
  const float* w_s = (const float*)d_in[4];
  const float* w_se = (const float*)d_in[5];
  const float* w_sc = (const float*)d_in[6];
  const float* w_s2e = (const float*)d_in[7];
  const float* w_e2s = (const float*)d_in[8];
  const float* w_s2c = (const float*)d_in[9];
  const float* w_c2s = (const float*)d_in[10];
  const float* ln_s_g = (const float*)d_in[11];
  const float* ln_s_b = (const float*)d_in[12];
  const float* ln_e_g = (const float*)d_in[13];
  const float* ln_e_b = (const float*)d_in[14];
  const float* ln_c_g = (const float*)d_in[15];
  const float* ln_c_b = (const float*)d_in[16];
  const float* pe_e[3] = {(const float*)d_in[17], (const float*)d_in[19], (const float*)d_in[21]};
  const float* pe_c[3] = {(const float*)d_in[18], (const float*)d_in[20], (const float*)d_in[22]};

  static const int NEXP[3] = {2151, 2253, 2458};
  static const int NCMP[3] = {1844, 1639, 1434};
  static const int NEXP_P[3] = {2176, 2304, 2560};
  static const int NCMP_P[3] = {1920, 1664, 1536};
  static const int LAYERS[3] = {2, 2, 1};
  static const float ALPHA[3][3] = {{0.3f, 0.25f, 0.15f}, {0.65f, 0.55f, 0.35f}, {1.0f, 0.9f, 0.8f}};

  const long SZ_S = 2L * SEQ * DIM;
  const long SZ_E = 2L * 2458 * DIM;
  const long SZ_C = 2L * 1844 * DIM;
  float* ws = (float*)d_ws;
  float* sS[2] = {ws, ws + SZ_S}; ws += 2 * SZ_S;
  float* sV[2] = {ws, ws + SZ_S}; ws += 2 * SZ_S;
  float* eS[2] = {ws, ws + SZ_E}; ws += 2 * SZ_E;
  float* eV[2] = {ws, ws + SZ_E}; ws += 2 * SZ_E;
  float* cS[2] = {ws, ws + SZ_C}; ws += 2 * SZ_C;
  float* cV[2] = {ws, ws + SZ_C}; ws += 2 * SZ_C;
  float* scores = ws; ws += 2L * 4096 * 2048;  // fits combined CR x SEQ and all squares
  __bf16* bw = (__bf16*)ws;
  __bf16* sb = bw;   bw += 2L * 2048 * DIM;
  __bf16* eb = bw;   bw += 2L * 2560 * DIM;
  __bf16* cb = bw;   bw += 2L * 1920 * DIM;
  __bf16* awb = bw;  bw += 2L * 4096 * DIM;   // combined e+c A panel
  __bf16* valb = bw; bw += 4096L * DIM;
  __bf16* rwT = bw;  bw += 32000L * DIM;

  auto cdiv = [](long a, long b) { return (int)((a + b - 1) / b); };

  k_embed<<<NB * SEQ, 128, 0, stream>>>(tokens, embed, sS[0], sV[0]);

  int cs = 0, li = 0;
  for (int st = 0; st < 3; ++st) {
    const int Ne = NEXP[st], Nc = NCMP[st];
    const int NeP = NEXP_P[st], NcP = NCMP_P[st];
    const int CR = NeP + NcP;                  // combined rows for s->e|c GEMM
    const float alpha = ALPHA[st][0], bs2b = ALPHA[st][1], bb2s = ALPHA[st][2];
    const float sc_x = 0.15f * bs2b * alpha;
    const float sc_b = 0.2f * alpha;
    const float sc_s = 0.15f * bb2s;
    int ce = 0, cc = 0;
    k_bcast2<<<cdiv((long)NB * NeP, 4), 256, 0, stream>>>(pe_e[st], eS[0], eV[0], eb, Ne, NeP);
    k_bcast2<<<cdiv((long)NB * NcP, 4), 256, 0, stream>>>(pe_c[st], cS[0], cV[0], cb, Nc, NcP);
    for (int l = 0; l < LAYERS[st]; ++l) {
      // 1. window prop
      k_window<<<NB * SEQ / 4, 256, 0, stream>>>(sS[cs], sV[cs], w_s + (long)li * DIM,
                                                 sS[cs ^ 1], sV[cs ^ 1], sb);
      cs ^= 1;
      // 2+3. s -> e and s -> c : ONE GEMM (shared B panel = sb), scores [CR][SEQ]
      k_cvt_aw<<<cdiv((long)NB * NeP, 4), 256, 0, stream>>>(eS[ce], w_s2e + (long)li * DIM, awb,
                                                            Ne, NeP, 0, CR);
      k_cvt_aw<<<cdiv((long)NB * NcP, 4), 256, 0, stream>>>(cS[cc], w_s2c + (long)li * DIM, awb,
                                                            Nc, NcP, NeP, CR);
      {
        dim3 g(SEQ / 128, CR / 128, NB);
        k_mfma_nt<false><<<g, 256, 0, stream>>>(awb, sb, scores, nullptr, CR, SEQ, SEQ, 0);
      }
      k_topk_update<<<cdiv((long)NB * Ne, 4), 256, 0, stream>>>(
          scores, CR, 0, SEQ, sS[cs], sV[cs], eS[ce], eV[ce], eS[ce ^ 1], eV[ce ^ 1],
          eb, NeP, Ne, SEQ, sc_x);
      ce ^= 1;
      k_topk_update<<<cdiv((long)NB * Nc, 4), 256, 0, stream>>>(
          scores, CR, NeP, SEQ, sS[cs], sV[cs], cS[cc], cV[cc], cS[cc ^ 1], cV[cc ^ 1],
          cb, NcP, Nc, SEQ, sc_x);
      cc ^= 1;
      // 4. e self
      k_cvt_aw<<<cdiv((long)NB * NeP, 4), 256, 0, stream>>>(eS[ce], w_se + (long)li * DIM, awb,
                                                            Ne, NeP, 0, NeP);
      {
        dim3 g(NeP / 128, NeP / 128, NB);
        k_mfma_nt<false><<<g, 256, 0, stream>>>(awb, eb, scores, nullptr, NeP, NeP, NeP, 0);
      }
      k_topk_update<<<cdiv((long)NB * Ne, 4), 256, 0, stream>>>(
          scores, NeP, 0, NeP, eS[ce], eV[ce], eS[ce], eV[ce], eS[ce ^ 1], eV[ce ^ 1],
          eb, NeP, Ne, Ne, sc_b);
      ce ^= 1;
      // 5. c self
      k_cvt_aw<<<cdiv((long)NB * NcP, 4), 256, 0, stream>>>(cS[cc], w_sc + (long)li * DIM, awb,
                                                            Nc, NcP, 0, NcP);
      {
        dim3 g(NcP / 128, NcP / 128, NB);
        k_mfma_nt<false><<<g, 256, 0, stream>>>(awb, cb, scores, nullptr, NcP, NcP, NcP, 0);
      }
      k_topk_update<<<cdiv((long)NB * Nc, 4), 256, 0, stream>>>(
          scores, NcP, 0, NcP, cS[cc], cV[cc], cS[cc], cV[cc], cS[cc ^ 1], cV[cc ^ 1],
          cb, NcP, Nc, Nc, sc_b);
      cc ^= 1;
      // 6a. e -> s
      k_cvt_aw<<<cdiv((long)NB * SEQ, 4), 256, 0, stream>>>(sS[cs], w_e2s + (long)li * DIM, awb,
                                                            SEQ, SEQ, 0, SEQ);
      {
        dim3 g(NeP / 128, SEQ / 128, NB);
        k_mfma_nt<false><<<g, 256, 0, stream>>>(awb, eb, scores, nullptr, SEQ, NeP, NeP, 0);
      }
      k_topk_update<<<NB * SEQ / 4, 256, 0, stream>>>(
          scores, SEQ, 0, NeP, eS[ce], eV[ce], sS[cs], sV[cs], sS[cs ^ 1], sV[cs ^ 1],
          nullptr, 0, SEQ, Ne, sc_s);
      // 6b. c -> s (accumulate in place)
      k_cvt_aw<<<cdiv((long)NB * SEQ, 4), 256, 0, stream>>>(sS[cs], w_c2s + (long)li * DIM, awb,
                                                            SEQ, SEQ, 0, SEQ);
      {
        dim3 g(NcP / 128, SEQ / 128, NB);
        k_mfma_nt<false><<<g, 256, 0, stream>>>(awb, cb, scores, nullptr, SEQ, NcP, NcP, 0);
      }
      k_topk_update<<<NB * SEQ / 4, 256, 0, stream>>>(
          scores, SEQ, 0, NcP, cS[cc], cV[cc], sS[cs ^ 1], sV[cs ^ 1], sS[cs ^ 1], sV[cs ^ 1],
          nullptr, 0, SEQ, Nc, sc_s);
      cs ^= 1;
      // 7. stabilize
      k_stab<<<NB * SEQ / 4, 256, 0, stream>>>(sS[cs], sV[cs], ln_s_g + (long)li * DIM,
                                               ln_s_b + (long)li * DIM, (long)NB * SEQ);
      k_stab<<<cdiv((long)NB * Ne, 4), 256, 0, stream>>>(eS[ce], eV[ce], ln_e_g + (long)li * DIM,
                                                         ln_e_b + (long)li * DIM, (long)NB * Ne);
      k_stab<<<cdiv((long)NB * Nc, 4), 256, 0, stream>>>(cS[cc], cV[cc], ln_c_g + (long)li * DIM,
                                                         ln_c_b + (long)li * DIM, (long)NB * Nc);
      ++li;
    }
  }
  // readout: m-fastest grid so the 128-row B panel stays L2-hot; NT stores for d_out
  k_cvt_val<<<NB * SEQ / 4, 256, 0, stream>>>(sV[cs], valb);
  {
    dim3 g(1000, 16);
    dim3 blk(32, 8);
    k_transpose_rw<<<g, blk, 0, stream>>>(readout_w, rwT);
  }
  {
    dim3 g((NB * SEQ) / 128, 32000 / 128, 1);
    k_mfma_nt<true><<<g, 256, 0, stream>>>(valb, rwT, (float*)d_out, readout_b, NB * SEQ, 32000,
                                           32000, 1);
  }
}

// Round 6
// 2345.228 us; speedup vs baseline: 1.6418x; 1.5702x over previous
//
#include <hip/hip_runtime.h>
#include <hip/hip_bf16.h>
#include <math.h>

#define DIM 512
#define SEQ 2048
#define NB 2
#define NEG_INF (-1e30f)

typedef __bf16 bf16x8 __attribute__((ext_vector_type(8)));
typedef float f32x4 __attribute__((ext_vector_type(4)));

static __device__ __forceinline__ float wave_sum(float x) {
#pragma unroll
  for (int off = 32; off; off >>= 1) x += __shfl_xor(x, off, 64);
  return x;
}

static __device__ __forceinline__ bf16x8 pack8(float4 a, float4 b) {
  bf16x8 r;
  r[0] = (__bf16)a.x; r[1] = (__bf16)a.y; r[2] = (__bf16)a.z; r[3] = (__bf16)a.w;
  r[4] = (__bf16)b.x; r[5] = (__bf16)b.y; r[6] = (__bf16)b.z; r[7] = (__bf16)b.w;
  return r;
}

static __device__ __forceinline__ void gload16(const void* g, void* l) {
  __builtin_amdgcn_global_load_lds((const __attribute__((address_space(1))) void*)g,
                                   (__attribute__((address_space(3))) void*)l, 16, 0, 0);
}

// ---------------- embed gather ----------------
__global__ __launch_bounds__(128) void k_embed(const int* __restrict__ tok,
                                               const float* __restrict__ emb,
                                               float* __restrict__ sS,
                                               float* __restrict__ sV) {
  long row = blockIdx.x;
  int t = tok[row];
  const float4* src = (const float4*)(emb + (long)t * DIM);
  float4* a = (float4*)(sS + row * DIM);
  float4* b = (float4*)(sV + row * DIM);
  int i = threadIdx.x;
  float4 v = src[i];
  a[i] = v;
  b[i] = v;
}

// ---------------- broadcast pe -> f32 state/val + zero-padded bf16 mirror ----------------
__global__ __launch_bounds__(256) void k_bcast2(const float* __restrict__ pe,
                                                float* __restrict__ s, float* __restrict__ v,
                                                __bf16* __restrict__ mb, int N, int Npad) {
  int wid = threadIdx.x >> 6, lane = threadIdx.x & 63;
  long row = (long)blockIdx.x * 4 + wid;
  if (row >= (long)NB * Npad) return;
  int b = (int)(row / Npad), m = (int)(row % Npad);
  int d0 = lane * 8;
  if (m < N) {
    float4 x0 = *(const float4*)(pe + (long)m * DIM + d0);
    float4 x1 = *(const float4*)(pe + (long)m * DIM + d0 + 4);
    long fo = ((long)b * N + m) * DIM + d0;
    *(float4*)(s + fo) = x0; *(float4*)(s + fo + 4) = x1;
    *(float4*)(v + fo) = x0; *(float4*)(v + fo + 4) = x1;
    *(bf16x8*)(mb + row * DIM + d0) = pack8(x0, x1);
  } else {
    bf16x8 z;
#pragma unroll
    for (int i = 0; i < 8; ++i) z[i] = (__bf16)0.f;
    *(bf16x8*)(mb + row * DIM + d0) = z;
  }
}

// ---------------- A-side cvt: out_bf16[b][Mpad][512] = state*w (pad rows = 0) ----------------
__global__ __launch_bounds__(256) void k_cvt_aw(const float* __restrict__ in,
                                                const float* __restrict__ w,
                                                __bf16* __restrict__ out, int M, int Mpad) {
  int wid = threadIdx.x >> 6, lane = threadIdx.x & 63;
  long row = (long)blockIdx.x * 4 + wid;
  if (row >= (long)NB * Mpad) return;
  int b = (int)(row / Mpad), m = (int)(row % Mpad);
  int d0 = lane * 8;
  if (m < M) {
    long fo = ((long)b * M + m) * DIM + d0;
    float4 x0 = *(const float4*)(in + fo);
    float4 x1 = *(const float4*)(in + fo + 4);
    float4 w0 = *(const float4*)(w + d0);
    float4 w1 = *(const float4*)(w + d0 + 4);
    x0.x *= w0.x; x0.y *= w0.y; x0.z *= w0.z; x0.w *= w0.w;
    x1.x *= w1.x; x1.y *= w1.y; x1.z *= w1.z; x1.w *= w1.w;
    *(bf16x8*)(out + row * DIM + d0) = pack8(x0, x1);
  } else {
    bf16x8 z;
#pragma unroll
    for (int i = 0; i < 8; ++i) z[i] = (__bf16)0.f;
    *(bf16x8*)(out + row * DIM + d0) = z;
  }
}

// ---------------- plain f32->bf16 rows (readout A) ----------------
__global__ __launch_bounds__(256) void k_cvt_val(const float* __restrict__ in,
                                                 __bf16* __restrict__ out) {
  int wid = threadIdx.x >> 6, lane = threadIdx.x & 63;
  long row = (long)blockIdx.x * 4 + wid;
  int d0 = lane * 8;
  float4 x0 = *(const float4*)(in + row * DIM + d0);
  float4 x1 = *(const float4*)(in + row * DIM + d0 + 4);
  *(bf16x8*)(out + row * DIM + d0) = pack8(x0, x1);
}

// ---------------- readout_w transpose+cvt: f32[512][32000] -> bf16[32000][512] ----------------
__global__ __launch_bounds__(256) void k_transpose_rw(const float* __restrict__ in,
                                                      __bf16* __restrict__ out) {
  __shared__ float t[32][33];
  int tx = threadIdx.x, ty = threadIdx.y;
  int n0 = blockIdx.x * 32, k0 = blockIdx.y * 32;
#pragma unroll
  for (int i = 0; i < 4; ++i)
    t[ty + i * 8][tx] = in[(long)(k0 + ty + i * 8) * 32000 + n0 + tx];
  __syncthreads();
#pragma unroll
  for (int i = 0; i < 4; ++i)
    out[(long)(n0 + ty + i * 8) * DIM + k0 + tx] = (__bf16)t[tx][ty + i * 8];
}

// ---------------- causal window-4 propagation (writes f32 out + bf16 state mirror) ------
__global__ __launch_bounds__(256) void k_window(const float* __restrict__ sS,
                                                const float* __restrict__ sV,
                                                const float* __restrict__ w,
                                                float* __restrict__ oS,
                                                float* __restrict__ oV,
                                                __bf16* __restrict__ oSb) {
  int wid = threadIdx.x >> 6, lane = threadIdx.x & 63;
  long row = (long)blockIdx.x * 4 + wid;
  int i = (int)(row & (SEQ - 1));
  int d0 = lane * 8;
  const float* ps = sS + row * DIM + d0;
  const float* pv = sV + row * DIM + d0;
  float4 s0 = *(const float4*)ps;
  float4 s1 = *(const float4*)(ps + 4);
  float4 w0 = *(const float4*)(w + d0);
  float4 w1 = *(const float4*)(w + d0 + 4);
  float4 aw0 = make_float4(s0.x * w0.x, s0.y * w0.y, s0.z * w0.z, s0.w * w0.w);
  float4 aw1 = make_float4(s1.x * w1.x, s1.y * w1.y, s1.z * w1.z, s1.w * w1.w);
  float4 nS0[4], nS1[4], nV0[4], nV1[4];
  float sc[4];
#pragma unroll
  for (int k = 0; k < 4; ++k) {
    bool valid = (i >= k + 1);
    const float* qs = ps - (long)(k + 1) * DIM;
    const float* qv = pv - (long)(k + 1) * DIM;
    if (valid) {
      nS0[k] = *(const float4*)qs;
      nS1[k] = *(const float4*)(qs + 4);
      nV0[k] = *(const float4*)qv;
      nV1[k] = *(const float4*)(qv + 4);
    } else {
      nS0[k] = make_float4(0.f, 0.f, 0.f, 0.f);
      nS1[k] = nS0[k]; nV0[k] = nS0[k]; nV1[k] = nS0[k];
    }
    sc[k] = aw0.x * nS0[k].x + aw0.y * nS0[k].y + aw0.z * nS0[k].z + aw0.w * nS0[k].w +
            aw1.x * nS1[k].x + aw1.y * nS1[k].y + aw1.z * nS1[k].z + aw1.w * nS1[k].w;
  }
#pragma unroll
  for (int k = 0; k < 4; ++k) sc[k] = wave_sum(sc[k]);
  float m = NEG_INF;
#pragma unroll
  for (int k = 0; k < 4; ++k)
    if (i >= k + 1 && sc[k] > m) m = sc[k];
  float p[4];
  float Z = 0.f;
#pragma unroll
  for (int k = 0; k < 4; ++k) {
    p[k] = (i >= k + 1) ? expf(sc[k] - m) : 0.f;
    Z += p[k];
  }
  float invZ = (Z > 0.f) ? (1.f / Z) : 0.f;
  float4 v0 = *(const float4*)pv;
  float4 v1 = *(const float4*)(pv + 4);
  float4 os0 = s0, os1 = s1, ov0 = v0, ov1 = v1;
#pragma unroll
  for (int k = 0; k < 4; ++k) {
    float c = 0.25f * p[k] * invZ;
    os0.x += c * nS0[k].x; os0.y += c * nS0[k].y; os0.z += c * nS0[k].z; os0.w += c * nS0[k].w;
    os1.x += c * nS1[k].x; os1.y += c * nS1[k].y; os1.z += c * nS1[k].z; os1.w += c * nS1[k].w;
    ov0.x += c * nV0[k].x; ov0.y += c * nV0[k].y; ov0.z += c * nV0[k].z; ov0.w += c * nV0[k].w;
    ov1.x += c * nV1[k].x; ov1.y += c * nV1[k].y; ov1.z += c * nV1[k].z; ov1.w += c * nV1[k].w;
  }
  *(float4*)(oS + row * DIM + d0) = os0;
  *(float4*)(oS + row * DIM + d0 + 4) = os1;
  *(float4*)(oV + row * DIM + d0) = ov0;
  *(float4*)(oV + row * DIM + d0 + 4) = ov1;
  *(bf16x8*)(oSb + row * DIM + d0) = pack8(os0, os1);
}

// ---------------- MFMA NT GEMM: C[b][m][n] = A[b][m][:] . B[b][n][:] (+bias) ----------------
// A: bf16 [B][Mpad][512], Bm: bf16 [B][Npad][512], C: f32 [B][Mpad][ldc]
// MODE 0: R2-exact (n-fastest grid, plain stores) — used for all score GEMMs.
// MODE 1: readout — m-fastest grid (B-panel L2 reuse) + non-temporal C stores.
template <int MODE>
__global__ __launch_bounds__(256) void k_mfma_nt(const __bf16* __restrict__ A,
                                                 const __bf16* __restrict__ Bm,
                                                 float* __restrict__ C,
                                                 const float* __restrict__ bias,
                                                 int Mpad, int Npad, int ldc) {
  __shared__ __align__(1024) char lds[16384];  // A 8KB | B 8KB
  const int tid = threadIdx.x;
  const int wid = tid >> 6, lane = tid & 63;
  const int b = blockIdx.z;
  const long m0 = (MODE ? (long)blockIdx.x : (long)blockIdx.y) * 128;
  const long n0 = (MODE ? (long)blockIdx.y : (long)blockIdx.x) * 128;
  const char* Ab = (const char*)(A + ((long)b * Mpad + m0) * DIM);
  const char* Bb = (const char*)(Bm + ((long)b * Npad + n0) * DIM);
  const int mw = (wid >> 1) * 64, nw = (wid & 1) * 64;

  // precompute staging source offsets (dest-linear, source pre-swizzled)
  int srow[2], scol[2], dofs[2];
#pragma unroll
  for (int is = 0; is < 2; ++is) {
    int d = is * 4096 + wid * 1024 + lane * 16;
    int s = d ^ (((d >> 8) & 3) << 4);
    srow[is] = s >> 6;        // tile row 0..127
    scol[is] = s & 63;        // byte within 64B row
    dofs[is] = is * 4096 + wid * 1024;  // wave-uniform LDS dest
  }
  // precompute swizzled fragment read offsets
  int aoff[4], boff[4];
#pragma unroll
  for (int f = 0; f < 4; ++f) {
    int rowA = mw + f * 16 + (lane & 15);
    int byA = rowA * 64 + (lane >> 4) * 16;
    aoff[f] = byA ^ (((byA >> 8) & 3) << 4);
    int rowB = nw + f * 16 + (lane & 15);
    int byB = rowB * 64 + (lane >> 4) * 16;
    boff[f] = (byB ^ (((byB >> 8) & 3) << 4)) + 8192;
  }

  f32x4 acc[4][4] = {};
  for (int k0 = 0; k0 < DIM; k0 += 32) {
    __syncthreads();
#pragma unroll
    for (int is = 0; is < 2; ++is) {
      gload16(Ab + (long)srow[is] * (DIM * 2) + k0 * 2 + scol[is], lds + dofs[is]);
      gload16(Bb + (long)srow[is] * (DIM * 2) + k0 * 2 + scol[is], lds + 8192 + dofs[is]);
    }
    asm volatile("s_waitcnt vmcnt(0)" ::: "memory");
    __syncthreads();
    bf16x8 af[4], bf[4];
#pragma unroll
    for (int f = 0; f < 4; ++f) {
      af[f] = *(const bf16x8*)(lds + aoff[f]);
      bf[f] = *(const bf16x8*)(lds + boff[f]);
    }
#pragma unroll
    for (int i = 0; i < 4; ++i)
#pragma unroll
      for (int j = 0; j < 4; ++j)
        acc[i][j] = __builtin_amdgcn_mfma_f32_16x16x32_bf16(af[i], bf[j], acc[i][j], 0, 0, 0);
  }
  float* Cb = C + ((long)b * Mpad + m0) * ldc + n0;
#pragma unroll
  for (int i = 0; i < 4; ++i) {
    int mrow = mw + i * 16 + (lane >> 4) * 4;
#pragma unroll
    for (int r = 0; r < 4; ++r) {
      long moff = (long)(mrow + r) * ldc;
#pragma unroll
      for (int j = 0; j < 4; ++j) {
        int ncol = nw + j * 16 + (lane & 15);
        float v = acc[i][j][r];
        if (bias) v += bias[n0 + ncol];
        if (MODE)
          __builtin_nontemporal_store(v, &Cb[moff + ncol]);
        else
          Cb[moff + ncol] = v;
      }
    }
  }
}

// ---------------- fused top-4 + softmax + gather + update (+optional bf16 mirror) --------
__global__ __launch_bounds__(256) void k_topk_update(
    const float* __restrict__ scores, int Mpad, int ldc,
    const float* __restrict__ srcS, const float* __restrict__ srcV,
    const float* __restrict__ baseS, const float* __restrict__ baseV,
    float* __restrict__ outS, float* __restrict__ outV,
    __bf16* __restrict__ outSb, int MpadMir,
    int M, int N, float scale) {
  int wid = threadIdx.x >> 6, lane = threadIdx.x & 63;
  long row = (long)blockIdx.x * 4 + wid;
  long total = (long)NB * M;
  if (row >= total) return;
  int b = (int)(row / M);
  int m = (int)(row - (long)b * M);
  const float* sc = scores + ((long)b * Mpad + m) * ldc;
  float v0 = NEG_INF, v1 = NEG_INF, v2 = NEG_INF, v3 = NEG_INF;
  int i0 = 0x7fffffff, i1 = 0x7fffffff, i2 = 0x7fffffff, i3 = 0x7fffffff;
  for (int s = lane; s < N; s += 64) {
    float x = sc[s];
    if (x > v3) {
      if (x > v0) { v3 = v2; i3 = i2; v2 = v1; i2 = i1; v1 = v0; i1 = i0; v0 = x; i0 = s; }
      else if (x > v1) { v3 = v2; i3 = i2; v2 = v1; i2 = i1; v1 = x; i1 = s; }
      else if (x > v2) { v3 = v2; i3 = i2; v2 = x; i2 = s; }
      else { v3 = x; i3 = s; }
    }
  }
  int ptr = 0;
  float rv[4];
  int ri[4];
#pragma unroll
  for (int r = 0; r < 4; ++r) {
    float cv = (ptr == 0) ? v0 : (ptr == 1) ? v1 : (ptr == 2) ? v2 : (ptr == 3) ? v3 : NEG_INF;
    int ci = (ptr == 0) ? i0 : (ptr == 1) ? i1 : (ptr == 2) ? i2 : (ptr == 3) ? i3 : 0x7fffffff;
    float bv = cv;
    int bi = ci;
#pragma unroll
    for (int off = 32; off; off >>= 1) {
      float ov = __shfl_xor(bv, off, 64);
      int oi = __shfl_xor(bi, off, 64);
      if (ov > bv || (ov == bv && oi < bi)) { bv = ov; bi = oi; }
    }
    rv[r] = bv;
    ri[r] = bi;
    if (bi == ci) ptr++;
  }
  float p0 = 1.f, p1 = expf(rv[1] - rv[0]), p2 = expf(rv[2] - rv[0]), p3 = expf(rv[3] - rv[0]);
  float invZ = 1.f / (p0 + p1 + p2 + p3);
  p0 *= invZ; p1 *= invZ; p2 *= invZ; p3 *= invZ;
  int d0 = lane * 8;
  long sb = (long)b * N;
  const float* gs0 = srcS + (sb + ri[0]) * DIM + d0;
  const float* gs1 = srcS + (sb + ri[1]) * DIM + d0;
  const float* gs2 = srcS + (sb + ri[2]) * DIM + d0;
  const float* gs3 = srcS + (sb + ri[3]) * DIM + d0;
  const float* gv0 = srcV + (sb + ri[0]) * DIM + d0;
  const float* gv1 = srcV + (sb + ri[1]) * DIM + d0;
  const float* gv2 = srcV + (sb + ri[2]) * DIM + d0;
  const float* gv3 = srcV + (sb + ri[3]) * DIM + d0;
  long ro = row * DIM + d0;
  float4 osv[2];
#pragma unroll
  for (int h = 0; h < 2; ++h) {
    float4 x0 = *(const float4*)(gs0 + h * 4);
    float4 x1 = *(const float4*)(gs1 + h * 4);
    float4 x2 = *(const float4*)(gs2 + h * 4);
    float4 x3 = *(const float4*)(gs3 + h * 4);
    float4 o = *(const float4*)(baseS + ro + h * 4);
    o.x += scale * (p0 * x0.x + p1 * x1.x + p2 * x2.x + p3 * x3.x);
    o.y += scale * (p0 * x0.y + p1 * x1.y + p2 * x2.y + p3 * x3.y);
    o.z += scale * (p0 * x0.z + p1 * x1.z + p2 * x2.z + p3 * x3.z);
    o.w += scale * (p0 * x0.w + p1 * x1.w + p2 * x2.w + p3 * x3.w);
    *(float4*)(outS + ro + h * 4) = o;
    osv[h] = o;
    float4 y0 = *(const float4*)(gv0 + h * 4);
    float4 y1 = *(const float4*)(gv1 + h * 4);
    float4 y2 = *(const float4*)(gv2 + h * 4);
    float4 y3 = *(const float4*)(gv3 + h * 4);
    float4 q = *(const float4*)(baseV + ro + h * 4);
    q.x += scale * (p0 * y0.x + p1 * y1.x + p2 * y2.x + p3 * y3.x);
    q.y += scale * (p0 * y0.y + p1 * y1.y + p2 * y2.y + p3 * y3.y);
    q.z += scale * (p0 * y0.z + p1 * y1.z + p2 * y2.z + p3 * y3.z);
    q.w += scale * (p0 * y0.w + p1 * y1.w + p2 * y2.w + p3 * y3.w);
    *(float4*)(outV + ro + h * 4) = q;
  }
  if (outSb) {
    *(bf16x8*)(outSb + ((long)b * MpadMir + m) * DIM + d0) = pack8(osv[0], osv[1]);
  }
}

// ---------------- stabilize ----------------
__global__ __launch_bounds__(256) void k_stab(float* __restrict__ state,
                                              float* __restrict__ val,
                                              const float* __restrict__ g,
                                              const float* __restrict__ beta, long rows) {
  int wid = threadIdx.x >> 6, lane = threadIdx.x & 63;
  long row = (long)blockIdx.x * 4 + wid;
  if (row >= rows) return;
  int d0 = lane * 8;
  float* ps = state + row * DIM + d0;
  float4 s0 = *(float4*)ps;
  float4 s1 = *(float4*)(ps + 4);
  s0.x = tanhf(s0.x); s0.y = tanhf(s0.y); s0.z = tanhf(s0.z); s0.w = tanhf(s0.w);
  s1.x = tanhf(s1.x); s1.y = tanhf(s1.y); s1.z = tanhf(s1.z); s1.w = tanhf(s1.w);
  *(float4*)ps = s0;
  *(float4*)(ps + 4) = s1;
  float* pv = val + row * DIM + d0;
  float4 x0 = *(float4*)pv;
  float4 x1 = *(float4*)(pv + 4);
  float sum = x0.x + x0.y + x0.z + x0.w + x1.x + x1.y + x1.z + x1.w;
  sum = wave_sum(sum);
  float mu = sum * (1.f / DIM);
  float d[8] = {x0.x - mu, x0.y - mu, x0.z - mu, x0.w - mu,
                x1.x - mu, x1.y - mu, x1.z - mu, x1.w - mu};
  float ss = d[0]*d[0] + d[1]*d[1] + d[2]*d[2] + d[3]*d[3] + d[4]*d[4] + d[5]*d[5] + d[6]*d[6] + d[7]*d[7];
  ss = wave_sum(ss);
  float rs = rsqrtf(ss * (1.f / DIM) + 1e-5f);
  float4 g0 = *(const float4*)(g + d0);
  float4 g1 = *(const float4*)(g + d0 + 4);
  float4 b0 = *(const float4*)(beta + d0);
  float4 b1 = *(const float4*)(beta + d0 + 4);
  x0.x = d[0] * rs * g0.x + b0.x; x0.y = d[1] * rs * g0.y + b0.y;
  x0.z = d[2] * rs * g0.z + b0.z; x0.w = d[3] * rs * g0.w + b0.w;
  x1.x = d[4] * rs * g1.x + b1.x; x1.y = d[5] * rs * g1.y + b1.y;
  x1.z = d[6] * rs * g1.z + b1.z; x1.w = d[7] * rs * g1.w + b1.w;
  *(float4*)pv = x0;
  *(float4*)(pv + 4) = x1;
}

// =======================================================================
extern "C" void kernel_launch(void* const* d_in, const int* in_sizes, int n_in,
                              void* d_out, int out_size, void* d_ws, size_t ws_size,
                              hipStream_t stream) {
  (void)in_sizes; (void)n_in; (void)out_size; (void)ws_size;
  const int* tokens = (const int*)d_in[0];
  const float* embed = (const float*)d_in[1];
  const float* readout_w = (const float*)d_in[2];
  const float* readout_b = (const float*)d_in[3];
  const float* w_s = (const float*)d_in[4];
  const float* w_se = (const float*)d_in[5];
  const float* w_sc = (const float*)d_in[6];
  const float* w_s2e = (const float*)d_in[7];
  const float* w_e2s = (const float*)d_in[8];
  const float* w_s2c = (const float*)d_in[9];
  const float* w_c2s = (const float*)d_in[10];
  const float* ln_s_g = (const float*)d_in[11];
  const float* ln_s_b = (const float*)d_in[12];
  const float* ln_e_g = (const float*)d_in[13];
  const float* ln_e_b = (const float*)d_in[14];
  const float* ln_c_g = (const float*)d_in[15];
  const float* ln_c_b = (const float*)d_in[16];
  const float* pe_e[3] = {(const float*)d_in[17], (const float*)d_in[19], (const float*)d_in[21]};
  const float* pe_c[3] = {(const float*)d_in[18], (const float*)d_in[20], (const float*)d_in[22]};

  static const int NEXP[3] = {2151, 2253, 2458};
  static const int NCMP[3] = {1844, 1639, 1434};
  static const int NEXP_P[3] = {2176, 2304, 2560};
  static const int NCMP_P[3] = {1920, 1664, 1536};
  static const int LAYERS[3] = {2, 2, 1};
  static const float ALPHA[3][3] = {{0.3f, 0.25f, 0.15f}, {0.65f, 0.55f, 0.35f}, {1.0f, 0.9f, 0.8f}};

  const long SZ_S = 2L * SEQ * DIM;
  const long SZ_E = 2L * 2458 * DIM;
  const long SZ_C = 2L * 1844 * DIM;
  float* ws = (float*)d_ws;
  float* sS[2] = {ws, ws + SZ_S}; ws += 2 * SZ_S;
  float* sV[2] = {ws, ws + SZ_S}; ws += 2 * SZ_S;
  float* eS[2] = {ws, ws + SZ_E}; ws += 2 * SZ_E;
  float* eV[2] = {ws, ws + SZ_E}; ws += 2 * SZ_E;
  float* cS[2] = {ws, ws + SZ_C}; ws += 2 * SZ_C;
  float* cV[2] = {ws, ws + SZ_C}; ws += 2 * SZ_C;
  float* scores = ws; ws += 2L * 2560 * 2560;
  __bf16* bw = (__bf16*)ws;
  __bf16* sb = bw;   bw += 2L * 2048 * DIM;
  __bf16* eb = bw;   bw += 2L * 2560 * DIM;
  __bf16* cb = bw;   bw += 2L * 1920 * DIM;
  __bf16* awb = bw;  bw += 2L * 2560 * DIM;
  __bf16* valb = bw; bw += 4096L * DIM;
  __bf16* rwT = bw;  bw += 32000L * DIM;

  auto cdiv = [](long a, long b) { return (int)((a + b - 1) / b); };

  k_embed<<<NB * SEQ, 128, 0, stream>>>(tokens, embed, sS[0], sV[0]);

  int cs = 0, li = 0;
  for (int st = 0; st < 3; ++st) {
    const int Ne = NEXP[st], Nc = NCMP[st];
    const int NeP = NEXP_P[st], NcP = NCMP_P[st];
    const float alpha = ALPHA[st][0], bs2b = ALPHA[st][1], bb2s = ALPHA[st][2];
    const float sc_x = 0.15f * bs2b * alpha;
    const float sc_b = 0.2f * alpha;
    const float sc_s = 0.15f * bb2s;
    int ce = 0, cc = 0;
    k_bcast2<<<cdiv((long)NB * NeP, 4), 256, 0, stream>>>(pe_e[st], eS[0], eV[0], eb, Ne, NeP);
    k_bcast2<<<cdiv((long)NB * NcP, 4), 256, 0, stream>>>(pe_c[st], cS[0], cV[0], cb, Nc, NcP);
    for (int l = 0; l < LAYERS[st]; ++l) {
      // 1. window prop (writes new s f32 + sb mirror)
      k_window<<<NB * SEQ / 4, 256, 0, stream>>>(sS[cs], sV[cs], w_s + (long)li * DIM,
                                                 sS[cs ^ 1], sV[cs ^ 1], sb);
      cs ^= 1;
      // 2. s -> e
      k_cvt_aw<<<cdiv((long)NB * NeP, 4), 256, 0, stream>>>(eS[ce], w_s2e + (long)li * DIM, awb, Ne, NeP);
      {
        dim3 g(SEQ / 128, NeP / 128, NB);
        k_mfma_nt<0><<<g, 256, 0, stream>>>(awb, sb, scores, nullptr, NeP, SEQ, SEQ);
      }
      k_topk_update<<<cdiv((long)NB * Ne, 4), 256, 0, stream>>>(
          scores, NeP, SEQ, sS[cs], sV[cs], eS[ce], eV[ce], eS[ce ^ 1], eV[ce ^ 1],
          eb, NeP, Ne, SEQ, sc_x);
      ce ^= 1;
      // 3. s -> c
      k_cvt_aw<<<cdiv((long)NB * NcP, 4), 256, 0, stream>>>(cS[cc], w_s2c + (long)li * DIM, awb, Nc, NcP);
      {
        dim3 g(SEQ / 128, NcP / 128, NB);
        k_mfma_nt<0><<<g, 256, 0, stream>>>(awb, sb, scores, nullptr, NcP, SEQ, SEQ);
      }
      k_topk_update<<<cdiv((long)NB * Nc, 4), 256, 0, stream>>>(
          scores, NcP, SEQ, sS[cs], sV[cs], cS[cc], cV[cc], cS[cc ^ 1], cV[cc ^ 1],
          cb, NcP, Nc, SEQ, sc_x);
      cc ^= 1;
      // 4. e self
      k_cvt_aw<<<cdiv((long)NB * NeP, 4), 256, 0, stream>>>(eS[ce], w_se + (long)li * DIM, awb, Ne, NeP);
      {
        dim3 g(NeP / 128, NeP / 128, NB);
        k_mfma_nt<0><<<g, 256, 0, stream>>>(awb, eb, scores, nullptr, NeP, NeP, NeP);
      }
      k_topk_update<<<cdiv((long)NB * Ne, 4), 256, 0, stream>>>(
          scores, NeP, NeP, eS[ce], eV[ce], eS[ce], eV[ce], eS[ce ^ 1], eV[ce ^ 1],
          eb, NeP, Ne, Ne, sc_b);
      ce ^= 1;
      // 5. c self
      k_cvt_aw<<<cdiv((long)NB * NcP, 4), 256, 0, stream>>>(cS[cc], w_sc + (long)li * DIM, awb, Nc, NcP);
      {
        dim3 g(NcP / 128, NcP / 128, NB);
        k_mfma_nt<0><<<g, 256, 0, stream>>>(awb, cb, scores, nullptr, NcP, NcP, NcP);
      }
      k_topk_update<<<cdiv((long)NB * Nc, 4), 256, 0, stream>>>(
          scores, NcP, NcP, cS[cc], cV[cc], cS[cc], cV[cc], cS[cc ^ 1], cV[cc ^ 1],
          cb, NcP, Nc, Nc, sc_b);
      cc ^= 1;
      // 6a. e -> s
      k_cvt_aw<<<cdiv((long)NB * SEQ, 4), 256, 0, stream>>>(sS[cs], w_e2s + (long)li * DIM, awb, SEQ, SEQ);
      {
        dim3 g(NeP / 128, SEQ / 128, NB);
        k_mfma_nt<0><<<g, 256, 0, stream>>>(awb, eb, scores, nullptr, SEQ, NeP, NeP);
      }
      k_topk_update<<<NB * SEQ / 4, 256, 0, stream>>>(
          scores, SEQ, NeP, eS[ce], eV[ce], sS[cs], sV[cs], sS[cs ^ 1], sV[cs ^ 1],
          nullptr, 0, SEQ, Ne, sc_s);
      // 6b. c -> s (accumulate in place on sS[cs^1])
      k_cvt_aw<<<cdiv((long)NB * SEQ, 4), 256, 0, stream>>>(sS[cs], w_c2s + (long)li * DIM, awb, SEQ, SEQ);
      {
        dim3 g(NcP / 128, SEQ / 128, NB);
        k_mfma_nt<0><<<g, 256, 0, stream>>>(awb, cb, scores, nullptr, SEQ, NcP, NcP);
      }
      k_topk_update<<<NB * SEQ / 4, 256, 0, stream>>>(
          scores, SEQ, NcP, cS[cc], cV[cc], sS[cs ^ 1], sV[cs ^ 1], sS[cs ^ 1], sV[cs ^ 1],
          nullptr, 0, SEQ, Nc, sc_s);
      cs ^= 1;
      // 7. stabilize
      k_stab<<<NB * SEQ / 4, 256, 0, stream>>>(sS[cs], sV[cs], ln_s_g + (long)li * DIM,
                                               ln_s_b + (long)li * DIM, (long)NB * SEQ);
      k_stab<<<cdiv((long)NB * Ne, 4), 256, 0, stream>>>(eS[ce], eV[ce], ln_e_g + (long)li * DIM,
                                                         ln_e_b + (long)li * DIM, (long)NB * Ne);
      k_stab<<<cdiv((long)NB * Nc, 4), 256, 0, stream>>>(cS[cc], cV[cc], ln_c_g + (long)li * DIM,
                                                         ln_c_b + (long)li * DIM, (long)NB * Nc);
      ++li;
    }
  }
  // readout: MODE 1 = m-fastest grid (x indexes M) + non-temporal stores
  k_cvt_val<<<NB * SEQ / 4, 256, 0, stream>>>(sV[cs], valb);
  {
    dim3 g(1000, 16);
    dim3 blk(32, 8);
    k_transpose_rw<<<g, blk, 0, stream>>>(readout_w, rwT);
  }
  {
    dim3 g((NB * SEQ) / 128, 32000 / 128, 1);
    k_mfma_nt<1><<<g, 256, 0, stream>>>(valb, rwT, (float*)d_out, readout_b, NB * SEQ, 32000, 32000);
  }
}